// Round 17
// baseline (447.690 us; speedup 1.0000x reference)
//
#include <hip/hip_runtime.h>
#include <hip/hip_bf16.h>

typedef unsigned int uint;
typedef unsigned short ushort;

// Dims
#define Bn 16
#define Dd 256
#define Nn 4096
#define Hh 4
#define Kk 16
#define Vv 64
#define Rr 23
#define Cc 144   // 64 q + 16 k + 64 v
#define NRT 9    // 144/16 row-tiles

typedef short bf16x8s __attribute__((ext_vector_type(8)));
typedef float f32x4 __attribute__((ext_vector_type(4)));
typedef float f32x2v __attribute__((ext_vector_type(2)));

static __device__ __forceinline__ ushort f2bf(float f) {
    __hip_bfloat16 h = __float2bfloat16(f);
    return __builtin_bit_cast(ushort, h);
}
static __device__ __forceinline__ float bf2f(ushort u) {
    return __uint_as_float(((uint)u) << 16);
}
static __device__ __forceinline__ float bflo(uint u) { return __uint_as_float(u << 16); }
static __device__ __forceinline__ float bfhi(uint u) { return __uint_as_float(u & 0xffff0000u); }

// ---------------- Kernel 1: pack 144 BN-folded rows (bf16, A-fragment order) ----------------
__global__ __launch_bounds__(256) void pack_kernel(
    const float* __restrict__ Wq, const float* __restrict__ qg, const float* __restrict__ qb,
    const float* __restrict__ qm, const float* __restrict__ qv,
    const float* __restrict__ Wk, const float* __restrict__ Wv,
    const float* __restrict__ vg, const float* __restrict__ vb,
    const float* __restrict__ vm, const float* __restrict__ vvar,
    ushort* __restrict__ Wf16, float* __restrict__ bias) {
    int c = blockIdx.x;       // 0..143
    int d = threadIdx.x;      // 0..255
    float scale, bs;
    const float* src;
    if (c < 64) {
        scale = qg[c] * rsqrtf(qv[c] + 1e-5f);
        bs = qb[c] - qm[c] * scale;
        src = Wq + c * Dd;
    } else if (c < 80) {
        scale = 1.f; bs = 0.f;
        src = Wk + (c - 64) * Dd;
    } else {
        int j = c - 80;
        scale = vg[j] * rsqrtf(vvar[j] + 1e-5f);
        bs = vb[j] - vm[j] * scale;
        src = Wv + j * Dd;
    }
    int rt = c >> 4, lm = c & 15;
    int kk = d >> 5, hi = (d >> 3) & 3, j = d & 7;
    Wf16[((rt * 8 + kk) * 64 + hi * 16 + lm) * 8 + j] = f2bf(src[d] * scale);
    if (d == 0) bias[c] = bs;
}

// ---------------- Kernel 2: MFMA projection -> consumer-layout buffers (R14 version) ---------
__global__ __launch_bounds__(256, 4) void proj_mfma_kernel(
    const float* __restrict__ x, const ushort* __restrict__ Wf16,
    const float* __restrict__ bias,
    ushort* __restrict__ qbufT, float* __restrict__ kbuf,
    ushort* __restrict__ vbufT) {
    __shared__ ushort Wlds[NRT * 2 * 64 * 8];   // 18432 B (2 k-steps per phase)

    int b = blockIdx.y;
    int n0 = blockIdx.x * 64;
    int t = threadIdx.x;
    int w = t >> 6, l = t & 63;
    int lm = l & 15, hi = l >> 4;
    int n = n0 + w * 16 + lm;     // this lane's output column

    const uint* WfU = (const uint*)Wf16;
    uint* WldsU = (uint*)Wlds;

    f32x4 acc[NRT];
#pragma unroll
    for (int rt = 0; rt < NRT; rt++) acc[rt] = (f32x4){0.f, 0.f, 0.f, 0.f};

    const float* xb = x + (size_t)b * Dd * Nn + n;

#pragma unroll
    for (int p = 0; p < 4; p++) {
        int kb = p * 2;
        if (p) __syncthreads();
#pragma unroll
        for (int i = 0; i < 18; i++) {
            int flat = t + 256 * i;
            int f2 = flat >> 8;          // rt*2 + kkl
            int rt = f2 >> 1, kkl = f2 & 1;
            WldsU[flat] = WfU[((rt * 8 + kb + kkl) << 8) + (flat & 255)];
        }
        __syncthreads();

#pragma unroll
        for (int kkl = 0; kkl < 2; kkl++) {
            int kk = kb + kkl;
            const float* xp = xb + (size_t)(kk * 32 + hi * 8) * Nn;
            float f[8];
#pragma unroll
            for (int j = 0; j < 8; j++) f[j] = xp[(size_t)j * Nn];
            bf16x8s bfrag;
#pragma unroll
            for (int j = 0; j < 8; j++) bfrag[j] = (short)f2bf(f[j]);
#pragma unroll
            for (int rt = 0; rt < NRT; rt++) {
                bf16x8s afrag = *reinterpret_cast<const bf16x8s*>(
                    &Wlds[(size_t)((rt * 2 + kkl) * 64 + l) * 8]);
                acc[rt] = __builtin_amdgcn_mfma_f32_16x16x32_bf16(afrag, bfrag, acc[rt], 0, 0, 0);
            }
        }
    }

    // ---- epilogue ----
#pragma unroll
    for (int rr = 0; rr < 4; rr++) {
        int kc = hi * 4 + rr;
        kbuf[((size_t)b * 16 + kc) * Nn + n] = acc[4][rr] + bias[64 + kc];
    }

    __syncthreads();   // done reading Wlds; reuse as transpose buffer (exactly 18432 B)
    {
        int nl = w * 16 + lm;
#pragma unroll
        for (int rt = 0; rt < 4; rt++)
#pragma unroll
            for (int rr = 0; rr < 4; rr++) {
                int kq = hi * 4 + rr;
                Wlds[nl * 72 + kq * 4 + rt] = f2bf(acc[rt][rr] + bias[rt * 16 + kq]);
            }
#pragma unroll
        for (int rt = 5; rt < 9; rt++)
#pragma unroll
            for (int rr = 0; rr < 4; rr++) {
                int v = (rt - 5) * 16 + hi * 4 + rr;
                Wlds[4608 + nl * 72 + v] = f2bf(acc[rt][rr] + bias[80 + v]);
            }
    }
    __syncthreads();

#pragma unroll
    for (int m = 0; m < 2; m++) {
        int i = t + 256 * m;
        int row = i >> 3, seg = i & 7;
        uint4 u = *reinterpret_cast<const uint4*>(&Wlds[row * 72 + seg * 8]);
        *reinterpret_cast<uint4*>(&qbufT[((size_t)b * Nn + n0 + row) * 64 + seg * 8]) = u;
    }
#pragma unroll
    for (int m = 0; m < 2; m++) {
        int i = t + 256 * m;
        int row = i >> 3, seg = i & 7;
        uint4 u = *reinterpret_cast<const uint4*>(&Wlds[4608 + row * 72 + seg * 8]);
        *reinterpret_cast<uint4*>(&vbufT[((size_t)b * Nn + n0 + row) * 64 + seg * 8]) = u;
    }
}

// ---------------- Kernel 2b: g_kernel — gbuf + zero lam (replaces hipMemset) ----------------
__global__ __launch_bounds__(256) void g_kernel(
    const ushort* __restrict__ qbufT, const float* __restrict__ conv_w,
    ushort* __restrict__ gbuf, float* __restrict__ lam) {
    __shared__ float cws[Kk][24];   // [k][r], padded
    int b = blockIdx.y;
    int n = blockIdx.x * 256 + threadIdx.x;
    int t = threadIdx.x;
    for (int i = t; i < Kk * Rr; i += 256) cws[i / Rr][i % Rr] = conv_w[i];
    // zero lam (16*64 = 1024 floats per b) from the first block of each b row
    if (blockIdx.x == 0) {
        float4 z = {0.f, 0.f, 0.f, 0.f};
        *reinterpret_cast<float4*>(&lam[(size_t)b * Kk * Vv + t * 4]) = z;
    }
    __syncthreads();

    float qf[16][4];
    const uint4* qp = reinterpret_cast<const uint4*>(&qbufT[((size_t)b * Nn + n) * 64]);
#pragma unroll
    for (int m = 0; m < 8; m++) {
        uint4 u = qp[m];
        uint vals[4] = {u.x, u.y, u.z, u.w};
#pragma unroll
        for (int j = 0; j < 4; j++) {
            int idx = m * 8 + j * 2;        // = k*4 + h, h even
            int k = idx >> 2, h = idx & 3;
            qf[k][h]     = bflo(vals[j]);
            qf[k][h + 1] = bfhi(vals[j]);
        }
    }

#pragma unroll
    for (int r = 0; r < Rr; r++) {
        float g0 = 0.f, g1 = 0.f, g2 = 0.f, g3 = 0.f;
#pragma unroll
        for (int k = 0; k < 16; k++) {
            float c = cws[k][r];
            g0 += qf[k][0] * c;
            g1 += qf[k][1] * c;
            g2 += qf[k][2] * c;
            g3 += qf[k][3] * c;
        }
        uint2 o;
        o.x = ((uint)f2bf(g1) << 16) | (uint)f2bf(g0);
        o.y = ((uint)f2bf(g3) << 16) | (uint)f2bf(g2);
        *reinterpret_cast<uint2*>(&gbuf[(((size_t)b * Rr + r) * Nn + n) * 4]) = o;
    }
}

// ---------------- Kernel 3: softmax over n for k channels (kbuf) ----------------
__global__ __launch_bounds__(256) void softmax_kernel(float* __restrict__ kbuf) {
    int b = blockIdx.y, kc = blockIdx.x;
    float* row = kbuf + ((size_t)b * 16 + kc) * Nn;
    int t = threadIdx.x;
    float vals[16];
    float m = -1e30f;
#pragma unroll
    for (int i = 0; i < 16; i++) {
        vals[i] = row[t + 256 * i];
        m = fmaxf(m, vals[i]);
    }
#pragma unroll
    for (int off = 32; off; off >>= 1) m = fmaxf(m, __shfl_xor(m, off));
    __shared__ float sm[4], ss[4];
    int wave = t >> 6;
    if ((t & 63) == 0) sm[wave] = m;
    __syncthreads();
    m = fmaxf(fmaxf(sm[0], sm[1]), fmaxf(sm[2], sm[3]));
    float s = 0.f;
#pragma unroll
    for (int i = 0; i < 16; i++) {
        vals[i] = __expf(vals[i] - m);
        s += vals[i];
    }
#pragma unroll
    for (int off = 32; off; off >>= 1) s += __shfl_xor(s, off);
    if ((t & 63) == 0) ss[wave] = s;
    __syncthreads();
    s = ss[0] + ss[1] + ss[2] + ss[3];
    float inv = 1.f / s;
#pragma unroll
    for (int i = 0; i < 16; i++) row[t + 256 * i] = vals[i] * inv;
}

// ---------------- Kernel 4: lam_c[b][16][64] = sum_n kk*vv ----------------
#define NCHUNK 128
__global__ __launch_bounds__(256) void lamc_kernel(
    const float* __restrict__ kbuf, const ushort* __restrict__ vbufT,
    float* __restrict__ lam) {
    int b = blockIdx.y;
    int n0 = blockIdx.x * NCHUNK;
    __shared__ float kks[Kk][NCHUNK + 1];   // 8256 B
    __shared__ ushort vvT[NCHUNK][72];      // 18432 B, rows 144 B
    int t = threadIdx.x;
#pragma unroll
    for (int m = 0; m < 2; m++) {
        int i = t + 256 * m;
        int r = i >> 5, seg = i & 31;
        float4 f = *reinterpret_cast<const float4*>(&kbuf[((size_t)b * 16 + r) * Nn + n0 + seg * 4]);
        kks[r][seg * 4 + 0] = f.x;
        kks[r][seg * 4 + 1] = f.y;
        kks[r][seg * 4 + 2] = f.z;
        kks[r][seg * 4 + 3] = f.w;
    }
#pragma unroll
    for (int m = 0; m < 4; m++) {
        int i = t + 256 * m;
        int row = i >> 3, seg = i & 7;
        uint4 u = *reinterpret_cast<const uint4*>(&vbufT[((size_t)b * Nn + n0 + row) * 64 + seg * 8]);
        *reinterpret_cast<uint4*>(&vvT[row][seg * 8]) = u;
    }
    __syncthreads();
    int v = t & 63, k0 = t >> 6;
    float acc4[4] = {0.f, 0.f, 0.f, 0.f};
    for (int nl = 0; nl < NCHUNK; nl++) {
        float wv = bf2f(vvT[nl][v]);
#pragma unroll
        for (int j2 = 0; j2 < 4; j2++) acc4[j2] += kks[k0 + 4 * j2][nl] * wv;
    }
#pragma unroll
    for (int j2 = 0; j2 < 4; j2++)
        atomicAdd(&lam[((size_t)b * Kk + k0 + 4 * j2) * Vv + v], acc4[j2]);
}

// ---------------- Kernel 5: fused position-lambda + apply (explicit ILP) ----------------
// TN=32, 256 threads = (vgp 0..7)x(np 0..31). Register-batched g/q loads (one latency
// exposure) + rolling prefetch of vv/lcs -> LDS latency hidden under pk-FMA streams.
#define TN 32
__global__ __launch_bounds__(256, 4) void fused_out_kernel(
    const ushort* __restrict__ qbufT, const ushort* __restrict__ vbufT,
    const ushort* __restrict__ gbuf, const float* __restrict__ lam,
    const float* __restrict__ conv_b, float* __restrict__ out) {
    __shared__ ushort vvsT[54][72];       // [j][v] bf16; n = n0-11+j; rows 144 B
    __shared__ ushort qsT[TN][68];        // [np][k*4+h] bf16; rows 136 B
    __shared__ ushort gsT[Rr][TN][4];     // [r][np][h] bf16 (linear copy of gbuf chunk)
    __shared__ float  lcs[Kk][Vv];        // lam_c + conv_b

    int b = blockIdx.y;
    int n0 = blockIdx.x * TN;
    int t = threadIdx.x;

    // ---- load phase (all globals issued before any LDS write) ----
    uint4 gld0, gld1;
    {
        int i = t;
        int r = i >> 4, seg = i & 15;
        if (i < 368)
            gld0 = *reinterpret_cast<const uint4*>(&gbuf[(((size_t)b * Rr + r) * Nn + n0) * 4 + seg * 8]);
        int i2 = t + 256;
        int r2 = i2 >> 4, seg2 = i2 & 15;
        if (i2 < 368)
            gld1 = *reinterpret_cast<const uint4*>(&gbuf[(((size_t)b * Rr + r2) * Nn + n0) * 4 + seg2 * 8]);
    }
    uint2 qld0, qld1;
    {
        int i = t;
        int np = i >> 4, seg = i & 15;
        qld0 = *reinterpret_cast<const uint2*>(&qbufT[((size_t)b * Nn + n0 + np) * 64 + seg * 4]);
        int i2 = t + 256;
        int np2 = i2 >> 4, seg2 = i2 & 15;
        qld1 = *reinterpret_cast<const uint2*>(&qbufT[((size_t)b * Nn + n0 + np2) * 64 + seg2 * 4]);
    }
    uint4 vld0 = {0, 0, 0, 0}, vld1 = {0, 0, 0, 0};
    {
        int i = t;
        int j = i >> 3, seg = i & 7;
        int nn = n0 - 11 + j;
        if (nn >= 0 && nn < Nn)
            vld0 = *reinterpret_cast<const uint4*>(&vbufT[((size_t)b * Nn + nn) * 64 + seg * 8]);
        int i2 = t + 256;
        int j2 = i2 >> 3, seg2 = i2 & 7;
        int nn2 = n0 - 11 + j2;
        if (i2 < 432 && nn2 >= 0 && nn2 < Nn)
            vld1 = *reinterpret_cast<const uint4*>(&vbufT[((size_t)b * Nn + nn2) * 64 + seg2 * 8]);
    }
    float lld[4];
#pragma unroll
    for (int m = 0; m < 4; m++) {
        int i = t + 256 * m;
        lld[m] = lam[(size_t)b * Kk * Vv + i] + conv_b[i >> 6];
    }

    // ---- write phase ----
    {
        int i = t;
        if (i < 368) *(reinterpret_cast<uint4*>(gsT) + i) = gld0;
        int i2 = t + 256;
        if (i2 < 368) *(reinterpret_cast<uint4*>(gsT) + i2) = gld1;
    }
    {
        int i = t;
        int np = i >> 4, seg = i & 15;
        *reinterpret_cast<uint2*>(&qsT[np][seg * 4]) = qld0;
        int i2 = t + 256;
        int np2 = i2 >> 4, seg2 = i2 & 15;
        *reinterpret_cast<uint2*>(&qsT[np2][seg2 * 4]) = qld1;
    }
    {
        int i = t;
        int j = i >> 3, seg = i & 7;
        *reinterpret_cast<uint4*>(&vvsT[j][seg * 8]) = vld0;
        int i2 = t + 256;
        if (i2 < 432) {
            int j2 = i2 >> 3, seg2 = i2 & 7;
            *reinterpret_cast<uint4*>(&vvsT[j2][seg2 * 8]) = vld1;
        }
    }
#pragma unroll
    for (int m = 0; m < 4; m++) {
        int i = t + 256 * m;
        lcs[i >> 6][i & 63] = lld[m];
    }
    __syncthreads();

    // ---- main ----
    int np = t & 31;
    int vgp = t >> 5;

    f32x2v acc2[4][4];    // [h][v-pair]
#pragma unroll
    for (int h = 0; h < 4; h++)
#pragma unroll
        for (int vp = 0; vp < 4; vp++) acc2[h][vp] = (f32x2v){0.f, 0.f};

    // position: batch all g b64s (one exposure), rolling 4-deep vv prefetch
    ushort4 g4s[Rr];
#pragma unroll
    for (int r = 0; r < Rr; r++)
        g4s[r] = *reinterpret_cast<const ushort4*>(&gsT[r][np][0]);

    uint4 wbuf[4];
#pragma unroll
    for (int i = 0; i < 4; i++)
        wbuf[i] = *reinterpret_cast<const uint4*>(&vvsT[np + i][vgp * 8]);

#pragma unroll
    for (int r = 0; r < Rr; r++) {
        uint4 w4 = wbuf[r & 3];
        if (r + 4 < Rr)
            wbuf[r & 3] = *reinterpret_cast<const uint4*>(&vvsT[np + r + 4][vgp * 8]);
        float gh[4] = {bf2f(g4s[r].x), bf2f(g4s[r].y), bf2f(g4s[r].z), bf2f(g4s[r].w)};
        f32x2v wv2[4];
        wv2[0] = (f32x2v){bflo(w4.x), bfhi(w4.x)};
        wv2[1] = (f32x2v){bflo(w4.y), bfhi(w4.y)};
        wv2[2] = (f32x2v){bflo(w4.z), bfhi(w4.z)};
        wv2[3] = (f32x2v){bflo(w4.w), bfhi(w4.w)};
#pragma unroll
        for (int h = 0; h < 4; h++) {
            f32x2v gb = (f32x2v){gh[h], gh[h]};
#pragma unroll
            for (int vp = 0; vp < 4; vp++) acc2[h][vp] += gb * wv2[vp];
        }
    }

    // content: batch all q b64s (one exposure), 2-deep lcs prefetch
    ushort4 q4s[Kk];
#pragma unroll
    for (int k = 0; k < Kk; k++)
        q4s[k] = *reinterpret_cast<const ushort4*>(&qsT[np][k * 4]);

    float4 lbufA0, lbufA1, lbufB0, lbufB1;
    lbufA0 = reinterpret_cast<const float4*>(&lcs[0][vgp * 8])[0];
    lbufA1 = reinterpret_cast<const float4*>(&lcs[0][vgp * 8])[1];
    lbufB0 = reinterpret_cast<const float4*>(&lcs[1][vgp * 8])[0];
    lbufB1 = reinterpret_cast<const float4*>(&lcs[1][vgp * 8])[1];

#pragma unroll
    for (int k = 0; k < Kk; k++) {
        float4 la, lb;
        if ((k & 1) == 0) { la = lbufA0; lb = lbufA1; }
        else              { la = lbufB0; lb = lbufB1; }
        if (k + 2 < Kk) {
            if ((k & 1) == 0) {
                lbufA0 = reinterpret_cast<const float4*>(&lcs[k + 2][vgp * 8])[0];
                lbufA1 = reinterpret_cast<const float4*>(&lcs[k + 2][vgp * 8])[1];
            } else {
                lbufB0 = reinterpret_cast<const float4*>(&lcs[k + 2][vgp * 8])[0];
                lbufB1 = reinterpret_cast<const float4*>(&lcs[k + 2][vgp * 8])[1];
            }
        }
        float qh[4] = {bf2f(q4s[k].x), bf2f(q4s[k].y), bf2f(q4s[k].z), bf2f(q4s[k].w)};
        f32x2v lv2[4] = {(f32x2v){la.x, la.y}, (f32x2v){la.z, la.w},
                         (f32x2v){lb.x, lb.y}, (f32x2v){lb.z, lb.w}};
#pragma unroll
        for (int h = 0; h < 4; h++) {
            f32x2v qb = (f32x2v){qh[h], qh[h]};
#pragma unroll
            for (int vp = 0; vp < 4; vp++) acc2[h][vp] += qb * lv2[vp];
        }
    }

    // store: 32 coalesced b32 stores
    float* ob = out + (size_t)b * 256 * Nn + n0 + np;
#pragma unroll
    for (int h = 0; h < 4; h++)
#pragma unroll
        for (int vp = 0; vp < 4; vp++) {
            ob[(size_t)(h * 64 + vgp * 8 + 2 * vp + 0) * Nn] = acc2[h][vp][0];
            ob[(size_t)(h * 64 + vgp * 8 + 2 * vp + 1) * Nn] = acc2[h][vp][1];
        }
}

extern "C" void kernel_launch(void* const* d_in, const int* in_sizes, int n_in,
                              void* d_out, int out_size, void* d_ws, size_t ws_size,
                              hipStream_t stream) {
    const float* x      = (const float*)d_in[0];
    const float* Wq     = (const float*)d_in[1];
    const float* qg     = (const float*)d_in[2];
    const float* qb     = (const float*)d_in[3];
    const float* qm     = (const float*)d_in[4];
    const float* qv     = (const float*)d_in[5];
    const float* Wk     = (const float*)d_in[6];
    const float* Wv     = (const float*)d_in[7];
    const float* vg     = (const float*)d_in[8];
    const float* vb     = (const float*)d_in[9];
    const float* vm     = (const float*)d_in[10];
    const float* vvar   = (const float*)d_in[11];
    const float* conv_w = (const float*)d_in[12];
    const float* conv_b = (const float*)d_in[13];
    float* out = (float*)d_out;

    float* wsf = (float*)d_ws;
    ushort* Wf16  = (ushort*)wsf;                       // 36864 u16 = 18432 f
    float*  bias  = wsf + 18432;                        // 256 f
    float*  kbuf  = wsf + 18688;                        // 16*16*4096 = 1048576 f
    float*  lam   = wsf + 1067264;                      // 16384 f
    ushort* qbufT = (ushort*)(wsf + 1083648);           // 16*4096*64 u16 = 2097152 f
    ushort* vbufT = (ushort*)(wsf + 3180800);           // 16*4096*64 u16 = 2097152 f
    ushort* gbuf  = (ushort*)(wsf + 5277952);           // 16*23*4096*4 u16 = 3014656 f

    pack_kernel<<<Cc, 256, 0, stream>>>(Wq, qg, qb, qm, qv, Wk, Wv, vg, vb, vm, vvar,
                                        Wf16, bias);
    proj_mfma_kernel<<<dim3(Nn / 64, Bn), 256, 0, stream>>>(x, Wf16, bias,
                                                            qbufT, kbuf, vbufT);
    g_kernel<<<dim3(Nn / 256, Bn), 256, 0, stream>>>(qbufT, conv_w, gbuf, lam);
    softmax_kernel<<<dim3(Kk, Bn), 256, 0, stream>>>(kbuf);
    lamc_kernel<<<dim3(Nn / NCHUNK, Bn), 256, 0, stream>>>(kbuf, vbufT, lam);
    fused_out_kernel<<<dim3(Nn / TN, Bn), 256, 0, stream>>>(qbufT, vbufT, gbuf, lam,
                                                            conv_b, out);
}

// Round 18
// 73.732 us; speedup vs baseline: 6.0719x; 6.0719x over previous
//
#include <hip/hip_runtime.h>
#include <hip/hip_bf16.h>

typedef unsigned int uint;
typedef unsigned short ushort;

// Dims
#define Bn 16
#define Dd 256
#define Nn 4096
#define Hh 4
#define Kk 16
#define Vv 64
#define Rr 23
#define Cc 144   // 64 q + 16 k + 64 v
#define NRT 9    // 144/16 row-tiles

typedef short bf16x8s __attribute__((ext_vector_type(8)));
typedef float f32x4 __attribute__((ext_vector_type(4)));
typedef float f32x2v __attribute__((ext_vector_type(2)));

static __device__ __forceinline__ ushort f2bf(float f) {
    __hip_bfloat16 h = __float2bfloat16(f);
    return __builtin_bit_cast(ushort, h);
}
static __device__ __forceinline__ float bf2f(ushort u) {
    return __uint_as_float(((uint)u) << 16);
}
static __device__ __forceinline__ float bflo(uint u) { return __uint_as_float(u << 16); }
static __device__ __forceinline__ float bfhi(uint u) { return __uint_as_float(u & 0xffff0000u); }

// ---------------- Kernel 1: pack 144 BN-folded rows (bf16, A-fragment order) ----------------
__global__ __launch_bounds__(256) void pack_kernel(
    const float* __restrict__ Wq, const float* __restrict__ qg, const float* __restrict__ qb,
    const float* __restrict__ qm, const float* __restrict__ qv,
    const float* __restrict__ Wk, const float* __restrict__ Wv,
    const float* __restrict__ vg, const float* __restrict__ vb,
    const float* __restrict__ vm, const float* __restrict__ vvar,
    ushort* __restrict__ Wf16, float* __restrict__ bias) {
    int c = blockIdx.x;       // 0..143
    int d = threadIdx.x;      // 0..255
    float scale, bs;
    const float* src;
    if (c < 64) {
        scale = qg[c] * rsqrtf(qv[c] + 1e-5f);
        bs = qb[c] - qm[c] * scale;
        src = Wq + c * Dd;
    } else if (c < 80) {
        scale = 1.f; bs = 0.f;
        src = Wk + (c - 64) * Dd;
    } else {
        int j = c - 80;
        scale = vg[j] * rsqrtf(vvar[j] + 1e-5f);
        bs = vb[j] - vm[j] * scale;
        src = Wv + j * Dd;
    }
    int rt = c >> 4, lm = c & 15;
    int kk = d >> 5, hi = (d >> 3) & 3, j = d & 7;
    Wf16[((rt * 8 + kk) * 64 + hi * 16 + lm) * 8 + j] = f2bf(src[d] * scale);
    if (d == 0) bias[c] = bs;
}

// ---------------- Kernel 2: MFMA projection -> consumer-layout buffers (R14 version) ---------
__global__ __launch_bounds__(256, 4) void proj_mfma_kernel(
    const float* __restrict__ x, const ushort* __restrict__ Wf16,
    const float* __restrict__ bias,
    ushort* __restrict__ qbufT, float* __restrict__ kbuf,
    ushort* __restrict__ vbufT) {
    __shared__ ushort Wlds[NRT * 2 * 64 * 8];   // 18432 B (2 k-steps per phase)

    int b = blockIdx.y;
    int n0 = blockIdx.x * 64;
    int t = threadIdx.x;
    int w = t >> 6, l = t & 63;
    int lm = l & 15, hi = l >> 4;
    int n = n0 + w * 16 + lm;     // this lane's output column

    const uint* WfU = (const uint*)Wf16;
    uint* WldsU = (uint*)Wlds;

    f32x4 acc[NRT];
#pragma unroll
    for (int rt = 0; rt < NRT; rt++) acc[rt] = (f32x4){0.f, 0.f, 0.f, 0.f};

    const float* xb = x + (size_t)b * Dd * Nn + n;

#pragma unroll
    for (int p = 0; p < 4; p++) {
        int kb = p * 2;
        if (p) __syncthreads();
#pragma unroll
        for (int i = 0; i < 18; i++) {
            int flat = t + 256 * i;
            int f2 = flat >> 8;          // rt*2 + kkl
            int rt = f2 >> 1, kkl = f2 & 1;
            WldsU[flat] = WfU[((rt * 8 + kb + kkl) << 8) + (flat & 255)];
        }
        __syncthreads();

#pragma unroll
        for (int kkl = 0; kkl < 2; kkl++) {
            int kk = kb + kkl;
            const float* xp = xb + (size_t)(kk * 32 + hi * 8) * Nn;
            float f[8];
#pragma unroll
            for (int j = 0; j < 8; j++) f[j] = xp[(size_t)j * Nn];
            bf16x8s bfrag;
#pragma unroll
            for (int j = 0; j < 8; j++) bfrag[j] = (short)f2bf(f[j]);
#pragma unroll
            for (int rt = 0; rt < NRT; rt++) {
                bf16x8s afrag = *reinterpret_cast<const bf16x8s*>(
                    &Wlds[(size_t)((rt * 2 + kkl) * 64 + l) * 8]);
                acc[rt] = __builtin_amdgcn_mfma_f32_16x16x32_bf16(afrag, bfrag, acc[rt], 0, 0, 0);
            }
        }
    }

    // ---- epilogue ----
#pragma unroll
    for (int rr = 0; rr < 4; rr++) {
        int kc = hi * 4 + rr;
        kbuf[((size_t)b * 16 + kc) * Nn + n] = acc[4][rr] + bias[64 + kc];
    }

    __syncthreads();   // done reading Wlds; reuse as transpose buffer (exactly 18432 B)
    {
        int nl = w * 16 + lm;
#pragma unroll
        for (int rt = 0; rt < 4; rt++)
#pragma unroll
            for (int rr = 0; rr < 4; rr++) {
                int kq = hi * 4 + rr;
                Wlds[nl * 72 + kq * 4 + rt] = f2bf(acc[rt][rr] + bias[rt * 16 + kq]);
            }
#pragma unroll
        for (int rt = 5; rt < 9; rt++)
#pragma unroll
            for (int rr = 0; rr < 4; rr++) {
                int v = (rt - 5) * 16 + hi * 4 + rr;
                Wlds[4608 + nl * 72 + v] = f2bf(acc[rt][rr] + bias[80 + v]);
            }
    }
    __syncthreads();

#pragma unroll
    for (int m = 0; m < 2; m++) {
        int i = t + 256 * m;
        int row = i >> 3, seg = i & 7;
        uint4 u = *reinterpret_cast<const uint4*>(&Wlds[row * 72 + seg * 8]);
        *reinterpret_cast<uint4*>(&qbufT[((size_t)b * Nn + n0 + row) * 64 + seg * 8]) = u;
    }
#pragma unroll
    for (int m = 0; m < 2; m++) {
        int i = t + 256 * m;
        int row = i >> 3, seg = i & 7;
        uint4 u = *reinterpret_cast<const uint4*>(&Wlds[4608 + row * 72 + seg * 8]);
        *reinterpret_cast<uint4*>(&vbufT[((size_t)b * Nn + n0 + row) * 64 + seg * 8]) = u;
    }
}

// ---------------- Kernel 2b: g_kernel — gbuf + zero lam (replaces hipMemset) ----------------
__global__ __launch_bounds__(256) void g_kernel(
    const ushort* __restrict__ qbufT, const float* __restrict__ conv_w,
    ushort* __restrict__ gbuf, float* __restrict__ lam) {
    __shared__ float cws[Kk][24];   // [k][r], padded
    int b = blockIdx.y;
    int n = blockIdx.x * 256 + threadIdx.x;
    int t = threadIdx.x;
    for (int i = t; i < Kk * Rr; i += 256) cws[i / Rr][i % Rr] = conv_w[i];
    if (blockIdx.x == 0) {
        float4 z = {0.f, 0.f, 0.f, 0.f};
        *reinterpret_cast<float4*>(&lam[(size_t)b * Kk * Vv + t * 4]) = z;
    }
    __syncthreads();

    float qf[16][4];
    const uint4* qp = reinterpret_cast<const uint4*>(&qbufT[((size_t)b * Nn + n) * 64]);
#pragma unroll
    for (int m = 0; m < 8; m++) {
        uint4 u = qp[m];
        uint vals[4] = {u.x, u.y, u.z, u.w};
#pragma unroll
        for (int j = 0; j < 4; j++) {
            int idx = m * 8 + j * 2;        // = k*4 + h, h even
            int k = idx >> 2, h = idx & 3;
            qf[k][h]     = bflo(vals[j]);
            qf[k][h + 1] = bfhi(vals[j]);
        }
    }

#pragma unroll
    for (int r = 0; r < Rr; r++) {
        float g0 = 0.f, g1 = 0.f, g2 = 0.f, g3 = 0.f;
#pragma unroll
        for (int k = 0; k < 16; k++) {
            float c = cws[k][r];
            g0 += qf[k][0] * c;
            g1 += qf[k][1] * c;
            g2 += qf[k][2] * c;
            g3 += qf[k][3] * c;
        }
        uint2 o;
        o.x = ((uint)f2bf(g1) << 16) | (uint)f2bf(g0);
        o.y = ((uint)f2bf(g3) << 16) | (uint)f2bf(g2);
        *reinterpret_cast<uint2*>(&gbuf[(((size_t)b * Rr + r) * Nn + n) * 4]) = o;
    }
}

// ---------------- Kernel 3: softmax over n for k channels (kbuf) ----------------
__global__ __launch_bounds__(256) void softmax_kernel(float* __restrict__ kbuf) {
    int b = blockIdx.y, kc = blockIdx.x;
    float* row = kbuf + ((size_t)b * 16 + kc) * Nn;
    int t = threadIdx.x;
    float vals[16];
    float m = -1e30f;
#pragma unroll
    for (int i = 0; i < 16; i++) {
        vals[i] = row[t + 256 * i];
        m = fmaxf(m, vals[i]);
    }
#pragma unroll
    for (int off = 32; off; off >>= 1) m = fmaxf(m, __shfl_xor(m, off));
    __shared__ float sm[4], ss[4];
    int wave = t >> 6;
    if ((t & 63) == 0) sm[wave] = m;
    __syncthreads();
    m = fmaxf(fmaxf(sm[0], sm[1]), fmaxf(sm[2], sm[3]));
    float s = 0.f;
#pragma unroll
    for (int i = 0; i < 16; i++) {
        vals[i] = __expf(vals[i] - m);
        s += vals[i];
    }
#pragma unroll
    for (int off = 32; off; off >>= 1) s += __shfl_xor(s, off);
    if ((t & 63) == 0) ss[wave] = s;
    __syncthreads();
    s = ss[0] + ss[1] + ss[2] + ss[3];
    float inv = 1.f / s;
#pragma unroll
    for (int i = 0; i < 16; i++) row[t + 256 * i] = vals[i] * inv;
}

// ---------------- Kernel 4: lam_c[b][16][64] = sum_n kk*vv ----------------
#define NCHUNK 128
__global__ __launch_bounds__(256) void lamc_kernel(
    const float* __restrict__ kbuf, const ushort* __restrict__ vbufT,
    float* __restrict__ lam) {
    int b = blockIdx.y;
    int n0 = blockIdx.x * NCHUNK;
    __shared__ float kks[Kk][NCHUNK + 1];   // 8256 B
    __shared__ ushort vvT[NCHUNK][72];      // 18432 B, rows 144 B
    int t = threadIdx.x;
#pragma unroll
    for (int m = 0; m < 2; m++) {
        int i = t + 256 * m;
        int r = i >> 5, seg = i & 31;
        float4 f = *reinterpret_cast<const float4*>(&kbuf[((size_t)b * 16 + r) * Nn + n0 + seg * 4]);
        kks[r][seg * 4 + 0] = f.x;
        kks[r][seg * 4 + 1] = f.y;
        kks[r][seg * 4 + 2] = f.z;
        kks[r][seg * 4 + 3] = f.w;
    }
#pragma unroll
    for (int m = 0; m < 4; m++) {
        int i = t + 256 * m;
        int row = i >> 3, seg = i & 7;
        uint4 u = *reinterpret_cast<const uint4*>(&vbufT[((size_t)b * Nn + n0 + row) * 64 + seg * 8]);
        *reinterpret_cast<uint4*>(&vvT[row][seg * 8]) = u;
    }
    __syncthreads();
    int v = t & 63, k0 = t >> 6;
    float acc4[4] = {0.f, 0.f, 0.f, 0.f};
    for (int nl = 0; nl < NCHUNK; nl++) {
        float wv = bf2f(vvT[nl][v]);
#pragma unroll
        for (int j2 = 0; j2 < 4; j2++) acc4[j2] += kks[k0 + 4 * j2][nl] * wv;
    }
#pragma unroll
    for (int j2 = 0; j2 < 4; j2++)
        atomicAdd(&lam[((size_t)b * Kk + k0 + 4 * j2) * Vv + v], acc4[j2]);
}

// ---------------- Kernel 5: fused position-lambda + apply (paired-iteration ILP) ----------
// TN=32, 256 threads = (vgp 0..7)x(np 0..31). R15 body, but r/k iterations processed in
// PAIRS with named scalar temps: both iterations' LDS loads issue before either compute,
// halving exposed LDS latency. No local arrays beyond R15's proven wv2/acc2 pattern.
#define TN 32
__global__ __launch_bounds__(256, 4) void fused_out_kernel(
    const ushort* __restrict__ qbufT, const ushort* __restrict__ vbufT,
    const ushort* __restrict__ gbuf, const float* __restrict__ lam,
    const float* __restrict__ conv_b, float* __restrict__ out) {
    __shared__ ushort vvsT[54][72];       // [j][v] bf16; n = n0-11+j; rows 144 B
    __shared__ ushort qsT[TN][68];        // [np][k*4+h] bf16; rows 136 B
    __shared__ ushort gsT[Rr][TN][4];     // [r][np][h] bf16 (linear copy of gbuf chunk)
    __shared__ float  lcs[Kk][Vv];        // lam_c + conv_b

    int b = blockIdx.y;
    int n0 = blockIdx.x * TN;
    int t = threadIdx.x;

    // ---- load phase (all globals issued before any LDS write) ----
    uint4 gld0, gld1;
    {
        int i = t;
        int r = i >> 4, seg = i & 15;
        if (i < 368)
            gld0 = *reinterpret_cast<const uint4*>(&gbuf[(((size_t)b * Rr + r) * Nn + n0) * 4 + seg * 8]);
        int i2 = t + 256;
        int r2 = i2 >> 4, seg2 = i2 & 15;
        if (i2 < 368)
            gld1 = *reinterpret_cast<const uint4*>(&gbuf[(((size_t)b * Rr + r2) * Nn + n0) * 4 + seg2 * 8]);
    }
    uint2 qld0, qld1;
    {
        int i = t;
        int np = i >> 4, seg = i & 15;
        qld0 = *reinterpret_cast<const uint2*>(&qbufT[((size_t)b * Nn + n0 + np) * 64 + seg * 4]);
        int i2 = t + 256;
        int np2 = i2 >> 4, seg2 = i2 & 15;
        qld1 = *reinterpret_cast<const uint2*>(&qbufT[((size_t)b * Nn + n0 + np2) * 64 + seg2 * 4]);
    }
    uint4 vld0 = {0, 0, 0, 0}, vld1 = {0, 0, 0, 0};
    {
        int i = t;
        int j = i >> 3, seg = i & 7;
        int nn = n0 - 11 + j;
        if (nn >= 0 && nn < Nn)
            vld0 = *reinterpret_cast<const uint4*>(&vbufT[((size_t)b * Nn + nn) * 64 + seg * 8]);
        int i2 = t + 256;
        int j2 = i2 >> 3, seg2 = i2 & 7;
        int nn2 = n0 - 11 + j2;
        if (i2 < 432 && nn2 >= 0 && nn2 < Nn)
            vld1 = *reinterpret_cast<const uint4*>(&vbufT[((size_t)b * Nn + nn2) * 64 + seg2 * 8]);
    }
    float lld[4];
#pragma unroll
    for (int m = 0; m < 4; m++) {
        int i = t + 256 * m;
        lld[m] = lam[(size_t)b * Kk * Vv + i] + conv_b[i >> 6];
    }

    // ---- write phase ----
    {
        int i = t;
        if (i < 368) *(reinterpret_cast<uint4*>(gsT) + i) = gld0;
        int i2 = t + 256;
        if (i2 < 368) *(reinterpret_cast<uint4*>(gsT) + i2) = gld1;
    }
    {
        int i = t;
        int np = i >> 4, seg = i & 15;
        *reinterpret_cast<uint2*>(&qsT[np][seg * 4]) = qld0;
        int i2 = t + 256;
        int np2 = i2 >> 4, seg2 = i2 & 15;
        *reinterpret_cast<uint2*>(&qsT[np2][seg2 * 4]) = qld1;
    }
    {
        int i = t;
        int j = i >> 3, seg = i & 7;
        *reinterpret_cast<uint4*>(&vvsT[j][seg * 8]) = vld0;
        int i2 = t + 256;
        if (i2 < 432) {
            int j2 = i2 >> 3, seg2 = i2 & 7;
            *reinterpret_cast<uint4*>(&vvsT[j2][seg2 * 8]) = vld1;
        }
    }
#pragma unroll
    for (int m = 0; m < 4; m++) {
        int i = t + 256 * m;
        lcs[i >> 6][i & 63] = lld[m];
    }
    __syncthreads();

    // ---- main ----
    int np = t & 31;
    int vgp = t >> 5;

    f32x2v acc2[4][4];    // [h][v-pair]
#pragma unroll
    for (int h = 0; h < 4; h++)
#pragma unroll
        for (int vp = 0; vp < 4; vp++) acc2[h][vp] = (f32x2v){0.f, 0.f};

    // position: r in pairs — 4 independent LDS loads per pair, then both computes
#pragma unroll
    for (int rp = 0; rp < 11; rp++) {
        const int r0 = 2 * rp, r1 = r0 + 1;
        ushort4 gA = *reinterpret_cast<const ushort4*>(&gsT[r0][np][0]);
        uint4   wA = *reinterpret_cast<const uint4*>(&vvsT[np + r0][vgp * 8]);
        ushort4 gB = *reinterpret_cast<const ushort4*>(&gsT[r1][np][0]);
        uint4   wB = *reinterpret_cast<const uint4*>(&vvsT[np + r1][vgp * 8]);
        {
            float gh[4] = {bf2f(gA.x), bf2f(gA.y), bf2f(gA.z), bf2f(gA.w)};
            f32x2v wv2[4];
            wv2[0] = (f32x2v){bflo(wA.x), bfhi(wA.x)};
            wv2[1] = (f32x2v){bflo(wA.y), bfhi(wA.y)};
            wv2[2] = (f32x2v){bflo(wA.z), bfhi(wA.z)};
            wv2[3] = (f32x2v){bflo(wA.w), bfhi(wA.w)};
#pragma unroll
            for (int h = 0; h < 4; h++) {
                f32x2v gb = (f32x2v){gh[h], gh[h]};
#pragma unroll
                for (int vp = 0; vp < 4; vp++) acc2[h][vp] += gb * wv2[vp];
            }
        }
        {
            float gh[4] = {bf2f(gB.x), bf2f(gB.y), bf2f(gB.z), bf2f(gB.w)};
            f32x2v wv2[4];
            wv2[0] = (f32x2v){bflo(wB.x), bfhi(wB.x)};
            wv2[1] = (f32x2v){bflo(wB.y), bfhi(wB.y)};
            wv2[2] = (f32x2v){bflo(wB.z), bfhi(wB.z)};
            wv2[3] = (f32x2v){bflo(wB.w), bfhi(wB.w)};
#pragma unroll
            for (int h = 0; h < 4; h++) {
                f32x2v gb = (f32x2v){gh[h], gh[h]};
#pragma unroll
                for (int vp = 0; vp < 4; vp++) acc2[h][vp] += gb * wv2[vp];
            }
        }
    }
    {   // tail r = 22
        ushort4 gA = *reinterpret_cast<const ushort4*>(&gsT[22][np][0]);
        uint4   wA = *reinterpret_cast<const uint4*>(&vvsT[np + 22][vgp * 8]);
        float gh[4] = {bf2f(gA.x), bf2f(gA.y), bf2f(gA.z), bf2f(gA.w)};
        f32x2v wv2[4];
        wv2[0] = (f32x2v){bflo(wA.x), bfhi(wA.x)};
        wv2[1] = (f32x2v){bflo(wA.y), bfhi(wA.y)};
        wv2[2] = (f32x2v){bflo(wA.z), bfhi(wA.z)};
        wv2[3] = (f32x2v){bflo(wA.w), bfhi(wA.w)};
#pragma unroll
        for (int h = 0; h < 4; h++) {
            f32x2v gb = (f32x2v){gh[h], gh[h]};
#pragma unroll
            for (int vp = 0; vp < 4; vp++) acc2[h][vp] += gb * wv2[vp];
        }
    }

    // content: k in pairs — 6 independent LDS loads per pair, then both computes
#pragma unroll
    for (int kp = 0; kp < 8; kp++) {
        const int k0 = 2 * kp, k1 = k0 + 1;
        ushort4 qA = *reinterpret_cast<const ushort4*>(&qsT[np][k0 * 4]);
        float4 laA = reinterpret_cast<const float4*>(&lcs[k0][vgp * 8])[0];
        float4 lbA = reinterpret_cast<const float4*>(&lcs[k0][vgp * 8])[1];
        ushort4 qB = *reinterpret_cast<const ushort4*>(&qsT[np][k1 * 4]);
        float4 laB = reinterpret_cast<const float4*>(&lcs[k1][vgp * 8])[0];
        float4 lbB = reinterpret_cast<const float4*>(&lcs[k1][vgp * 8])[1];
        {
            float qh[4] = {bf2f(qA.x), bf2f(qA.y), bf2f(qA.z), bf2f(qA.w)};
            f32x2v lv2[4] = {(f32x2v){laA.x, laA.y}, (f32x2v){laA.z, laA.w},
                             (f32x2v){lbA.x, lbA.y}, (f32x2v){lbA.z, lbA.w}};
#pragma unroll
            for (int h = 0; h < 4; h++) {
                f32x2v qb = (f32x2v){qh[h], qh[h]};
#pragma unroll
                for (int vp = 0; vp < 4; vp++) acc2[h][vp] += qb * lv2[vp];
            }
        }
        {
            float qh[4] = {bf2f(qB.x), bf2f(qB.y), bf2f(qB.z), bf2f(qB.w)};
            f32x2v lv2[4] = {(f32x2v){laB.x, laB.y}, (f32x2v){laB.z, laB.w},
                             (f32x2v){lbB.x, lbB.y}, (f32x2v){lbB.z, lbB.w}};
#pragma unroll
            for (int h = 0; h < 4; h++) {
                f32x2v qb = (f32x2v){qh[h], qh[h]};
#pragma unroll
                for (int vp = 0; vp < 4; vp++) acc2[h][vp] += qb * lv2[vp];
            }
        }
    }

    // store: 32 coalesced b32 stores
    float* ob = out + (size_t)b * 256 * Nn + n0 + np;
#pragma unroll
    for (int h = 0; h < 4; h++)
#pragma unroll
        for (int vp = 0; vp < 4; vp++) {
            ob[(size_t)(h * 64 + vgp * 8 + 2 * vp + 0) * Nn] = acc2[h][vp][0];
            ob[(size_t)(h * 64 + vgp * 8 + 2 * vp + 1) * Nn] = acc2[h][vp][1];
        }
}

extern "C" void kernel_launch(void* const* d_in, const int* in_sizes, int n_in,
                              void* d_out, int out_size, void* d_ws, size_t ws_size,
                              hipStream_t stream) {
    const float* x      = (const float*)d_in[0];
    const float* Wq     = (const float*)d_in[1];
    const float* qg     = (const float*)d_in[2];
    const float* qb     = (const float*)d_in[3];
    const float* qm     = (const float*)d_in[4];
    const float* qv     = (const float*)d_in[5];
    const float* Wk     = (const float*)d_in[6];
    const float* Wv     = (const float*)d_in[7];
    const float* vg     = (const float*)d_in[8];
    const float* vb     = (const float*)d_in[9];
    const float* vm     = (const float*)d_in[10];
    const float* vvar   = (const float*)d_in[11];
    const float* conv_w = (const float*)d_in[12];
    const float* conv_b = (const float*)d_in[13];
    float* out = (float*)d_out;

    float* wsf = (float*)d_ws;
    ushort* Wf16  = (ushort*)wsf;                       // 36864 u16 = 18432 f
    float*  bias  = wsf + 18432;                        // 256 f
    float*  kbuf  = wsf + 18688;                        // 16*16*4096 = 1048576 f
    float*  lam   = wsf + 1067264;                      // 16384 f
    ushort* qbufT = (ushort*)(wsf + 1083648);           // 16*4096*64 u16 = 2097152 f
    ushort* vbufT = (ushort*)(wsf + 3180800);           // 16*4096*64 u16 = 2097152 f
    ushort* gbuf  = (ushort*)(wsf + 5277952);           // 16*23*4096*4 u16 = 3014656 f

    pack_kernel<<<Cc, 256, 0, stream>>>(Wq, qg, qb, qm, qv, Wk, Wv, vg, vb, vm, vvar,
                                        Wf16, bias);
    proj_mfma_kernel<<<dim3(Nn / 64, Bn), 256, 0, stream>>>(x, Wf16, bias,
                                                            qbufT, kbuf, vbufT);
    g_kernel<<<dim3(Nn / 256, Bn), 256, 0, stream>>>(qbufT, conv_w, gbuf, lam);
    softmax_kernel<<<dim3(Kk, Bn), 256, 0, stream>>>(kbuf);
    lamc_kernel<<<dim3(Nn / NCHUNK, Bn), 256, 0, stream>>>(kbuf, vbufT, lam);
    fused_out_kernel<<<dim3(Nn / TN, Bn), 256, 0, stream>>>(qbufT, vbufT, gbuf, lam,
                                                            conv_b, out);
}

// Round 19
// 67.029 us; speedup vs baseline: 6.6790x; 1.1000x over previous
//
#include <hip/hip_runtime.h>
#include <hip/hip_bf16.h>

typedef unsigned int uint;
typedef unsigned short ushort;

// Dims
#define Bn 16
#define Dd 256
#define Nn 4096
#define Hh 4
#define Kk 16
#define Vv 64
#define Rr 23
#define Cc 144   // 64 q + 16 k + 64 v
#define NRT 9    // 144/16 row-tiles

typedef short bf16x8s __attribute__((ext_vector_type(8)));
typedef float f32x4 __attribute__((ext_vector_type(4)));

static __device__ __forceinline__ ushort f2bf(float f) {
    __hip_bfloat16 h = __float2bfloat16(f);
    return __builtin_bit_cast(ushort, h);
}
static __device__ __forceinline__ float bf2f(ushort u) {
    return __uint_as_float(((uint)u) << 16);
}
static __device__ __forceinline__ float bflo(uint u) { return __uint_as_float(u << 16); }
static __device__ __forceinline__ float bfhi(uint u) { return __uint_as_float(u & 0xffff0000u); }

// ---------------- Kernel 1: pack 144 BN-folded rows (bf16, A-fragment order) ----------------
__global__ __launch_bounds__(256) void pack_kernel(
    const float* __restrict__ Wq, const float* __restrict__ qg, const float* __restrict__ qb,
    const float* __restrict__ qm, const float* __restrict__ qv,
    const float* __restrict__ Wk, const float* __restrict__ Wv,
    const float* __restrict__ vg, const float* __restrict__ vb,
    const float* __restrict__ vm, const float* __restrict__ vvar,
    ushort* __restrict__ Wf16, float* __restrict__ bias) {
    int c = blockIdx.x;       // 0..143
    int d = threadIdx.x;      // 0..255
    float scale, bs;
    const float* src;
    if (c < 64) {
        scale = qg[c] * rsqrtf(qv[c] + 1e-5f);
        bs = qb[c] - qm[c] * scale;
        src = Wq + c * Dd;
    } else if (c < 80) {
        scale = 1.f; bs = 0.f;
        src = Wk + (c - 64) * Dd;
    } else {
        int j = c - 80;
        scale = vg[j] * rsqrtf(vvar[j] + 1e-5f);
        bs = vb[j] - vm[j] * scale;
        src = Wv + j * Dd;
    }
    int rt = c >> 4, lm = c & 15;
    int kk = d >> 5, hi = (d >> 3) & 3, j = d & 7;
    Wf16[((rt * 8 + kk) * 64 + hi * 16 + lm) * 8 + j] = f2bf(src[d] * scale);
    if (d == 0) bias[c] = bs;
}

// ---------------- Kernel 2: MFMA projection -> consumer-layout buffers (R14 version) ---------
__global__ __launch_bounds__(256, 4) void proj_mfma_kernel(
    const float* __restrict__ x, const ushort* __restrict__ Wf16,
    const float* __restrict__ bias,
    ushort* __restrict__ qbufT, float* __restrict__ kbuf,
    ushort* __restrict__ vbufT) {
    __shared__ ushort Wlds[NRT * 2 * 64 * 8];   // 18432 B (2 k-steps per phase)

    int b = blockIdx.y;
    int n0 = blockIdx.x * 64;
    int t = threadIdx.x;
    int w = t >> 6, l = t & 63;
    int lm = l & 15, hi = l >> 4;
    int n = n0 + w * 16 + lm;     // this lane's output column

    const uint* WfU = (const uint*)Wf16;
    uint* WldsU = (uint*)Wlds;

    f32x4 acc[NRT];
#pragma unroll
    for (int rt = 0; rt < NRT; rt++) acc[rt] = (f32x4){0.f, 0.f, 0.f, 0.f};

    const float* xb = x + (size_t)b * Dd * Nn + n;

#pragma unroll
    for (int p = 0; p < 4; p++) {
        int kb = p * 2;
        if (p) __syncthreads();
#pragma unroll
        for (int i = 0; i < 18; i++) {
            int flat = t + 256 * i;
            int f2 = flat >> 8;          // rt*2 + kkl
            int rt = f2 >> 1, kkl = f2 & 1;
            WldsU[flat] = WfU[((rt * 8 + kb + kkl) << 8) + (flat & 255)];
        }
        __syncthreads();

#pragma unroll
        for (int kkl = 0; kkl < 2; kkl++) {
            int kk = kb + kkl;
            const float* xp = xb + (size_t)(kk * 32 + hi * 8) * Nn;
            float f[8];
#pragma unroll
            for (int j = 0; j < 8; j++) f[j] = xp[(size_t)j * Nn];
            bf16x8s bfrag;
#pragma unroll
            for (int j = 0; j < 8; j++) bfrag[j] = (short)f2bf(f[j]);
#pragma unroll
            for (int rt = 0; rt < NRT; rt++) {
                bf16x8s afrag = *reinterpret_cast<const bf16x8s*>(
                    &Wlds[(size_t)((rt * 2 + kkl) * 64 + l) * 8]);
                acc[rt] = __builtin_amdgcn_mfma_f32_16x16x32_bf16(afrag, bfrag, acc[rt], 0, 0, 0);
            }
        }
    }

    // ---- epilogue ----
#pragma unroll
    for (int rr = 0; rr < 4; rr++) {
        int kc = hi * 4 + rr;
        kbuf[((size_t)b * 16 + kc) * Nn + n] = acc[4][rr] + bias[64 + kc];
    }

    __syncthreads();   // done reading Wlds; reuse as transpose buffer (exactly 18432 B)
    {
        int nl = w * 16 + lm;
#pragma unroll
        for (int rt = 0; rt < 4; rt++)
#pragma unroll
            for (int rr = 0; rr < 4; rr++) {
                int kq = hi * 4 + rr;
                Wlds[nl * 72 + kq * 4 + rt] = f2bf(acc[rt][rr] + bias[rt * 16 + kq]);
            }
#pragma unroll
        for (int rt = 5; rt < 9; rt++)
#pragma unroll
            for (int rr = 0; rr < 4; rr++) {
                int v = (rt - 5) * 16 + hi * 4 + rr;
                Wlds[4608 + nl * 72 + v] = f2bf(acc[rt][rr] + bias[80 + v]);
            }
    }
    __syncthreads();

#pragma unroll
    for (int m = 0; m < 2; m++) {
        int i = t + 256 * m;
        int row = i >> 3, seg = i & 7;
        uint4 u = *reinterpret_cast<const uint4*>(&Wlds[row * 72 + seg * 8]);
        *reinterpret_cast<uint4*>(&qbufT[((size_t)b * Nn + n0 + row) * 64 + seg * 8]) = u;
    }
#pragma unroll
    for (int m = 0; m < 2; m++) {
        int i = t + 256 * m;
        int row = i >> 3, seg = i & 7;
        uint4 u = *reinterpret_cast<const uint4*>(&Wlds[4608 + row * 72 + seg * 8]);
        *reinterpret_cast<uint4*>(&vbufT[((size_t)b * Nn + n0 + row) * 64 + seg * 8]) = u;
    }
}

// ---------------- Kernel 2b: g_kernel — gbuf + zero lam (replaces hipMemset) ----------------
__global__ __launch_bounds__(256) void g_kernel(
    const ushort* __restrict__ qbufT, const float* __restrict__ conv_w,
    ushort* __restrict__ gbuf, float* __restrict__ lam) {
    __shared__ float cws[Kk][24];   // [k][r], padded
    int b = blockIdx.y;
    int n = blockIdx.x * 256 + threadIdx.x;
    int t = threadIdx.x;
    for (int i = t; i < Kk * Rr; i += 256) cws[i / Rr][i % Rr] = conv_w[i];
    if (blockIdx.x == 0) {
        float4 z = {0.f, 0.f, 0.f, 0.f};
        *reinterpret_cast<float4*>(&lam[(size_t)b * Kk * Vv + t * 4]) = z;
    }
    __syncthreads();

    float qf[16][4];
    const uint4* qp = reinterpret_cast<const uint4*>(&qbufT[((size_t)b * Nn + n) * 64]);
#pragma unroll
    for (int m = 0; m < 8; m++) {
        uint4 u = qp[m];
        uint vals[4] = {u.x, u.y, u.z, u.w};
#pragma unroll
        for (int j = 0; j < 4; j++) {
            int idx = m * 8 + j * 2;        // = k*4 + h, h even
            int k = idx >> 2, h = idx & 3;
            qf[k][h]     = bflo(vals[j]);
            qf[k][h + 1] = bfhi(vals[j]);
        }
    }

#pragma unroll
    for (int r = 0; r < Rr; r++) {
        float g0 = 0.f, g1 = 0.f, g2 = 0.f, g3 = 0.f;
#pragma unroll
        for (int k = 0; k < 16; k++) {
            float c = cws[k][r];
            g0 += qf[k][0] * c;
            g1 += qf[k][1] * c;
            g2 += qf[k][2] * c;
            g3 += qf[k][3] * c;
        }
        uint2 o;
        o.x = ((uint)f2bf(g1) << 16) | (uint)f2bf(g0);
        o.y = ((uint)f2bf(g3) << 16) | (uint)f2bf(g2);
        *reinterpret_cast<uint2*>(&gbuf[(((size_t)b * Rr + r) * Nn + n) * 4]) = o;
    }
}

// ---------------- Kernel 3: softmax over n for k channels (kbuf) ----------------
__global__ __launch_bounds__(256) void softmax_kernel(float* __restrict__ kbuf) {
    int b = blockIdx.y, kc = blockIdx.x;
    float* row = kbuf + ((size_t)b * 16 + kc) * Nn;
    int t = threadIdx.x;
    float vals[16];
    float m = -1e30f;
#pragma unroll
    for (int i = 0; i < 16; i++) {
        vals[i] = row[t + 256 * i];
        m = fmaxf(m, vals[i]);
    }
#pragma unroll
    for (int off = 32; off; off >>= 1) m = fmaxf(m, __shfl_xor(m, off));
    __shared__ float sm[4], ss[4];
    int wave = t >> 6;
    if ((t & 63) == 0) sm[wave] = m;
    __syncthreads();
    m = fmaxf(fmaxf(sm[0], sm[1]), fmaxf(sm[2], sm[3]));
    float s = 0.f;
#pragma unroll
    for (int i = 0; i < 16; i++) {
        vals[i] = __expf(vals[i] - m);
        s += vals[i];
    }
#pragma unroll
    for (int off = 32; off; off >>= 1) s += __shfl_xor(s, off);
    if ((t & 63) == 0) ss[wave] = s;
    __syncthreads();
    s = ss[0] + ss[1] + ss[2] + ss[3];
    float inv = 1.f / s;
#pragma unroll
    for (int i = 0; i < 16; i++) row[t + 256 * i] = vals[i] * inv;
}

// ---------------- Kernel 4: lam_c[b][16][64] = sum_n kk*vv ----------------
#define NCHUNK 128
__global__ __launch_bounds__(256) void lamc_kernel(
    const float* __restrict__ kbuf, const ushort* __restrict__ vbufT,
    float* __restrict__ lam) {
    int b = blockIdx.y;
    int n0 = blockIdx.x * NCHUNK;
    __shared__ float kks[Kk][NCHUNK + 1];   // 8256 B
    __shared__ ushort vvT[NCHUNK][72];      // 18432 B, rows 144 B
    int t = threadIdx.x;
#pragma unroll
    for (int m = 0; m < 2; m++) {
        int i = t + 256 * m;
        int r = i >> 5, seg = i & 31;
        float4 f = *reinterpret_cast<const float4*>(&kbuf[((size_t)b * 16 + r) * Nn + n0 + seg * 4]);
        kks[r][seg * 4 + 0] = f.x;
        kks[r][seg * 4 + 1] = f.y;
        kks[r][seg * 4 + 2] = f.z;
        kks[r][seg * 4 + 3] = f.w;
    }
#pragma unroll
    for (int m = 0; m < 4; m++) {
        int i = t + 256 * m;
        int row = i >> 3, seg = i & 7;
        uint4 u = *reinterpret_cast<const uint4*>(&vbufT[((size_t)b * Nn + n0 + row) * 64 + seg * 8]);
        *reinterpret_cast<uint4*>(&vvT[row][seg * 8]) = u;
    }
    __syncthreads();
    int v = t & 63, k0 = t >> 6;
    float acc4[4] = {0.f, 0.f, 0.f, 0.f};
    for (int nl = 0; nl < NCHUNK; nl++) {
        float wv = bf2f(vvT[nl][v]);
#pragma unroll
        for (int j2 = 0; j2 < 4; j2++) acc4[j2] += kks[k0 + 4 * j2][nl] * wv;
    }
#pragma unroll
    for (int j2 = 0; j2 < 4; j2++)
        atomicAdd(&lam[((size_t)b * Kk + k0 + 4 * j2) * Vv + v], acc4[j2]);
}

// ---------------- Kernel 5: fused output via MFMA ----------------
// out[v][n] (per h) = A (64x96) x S_h (96x32):
//   A cols 0..53 = vv window (n0-11 .. n0+42), cols 54..69 = lam_c+conv_b (bf16), 70..95 = 0
//   S_h rows m<54: banded g: S[m][n] = g[h][m-n][n] for 0<=m-n<23; rows 54..69 = q[k][h][n]
// Fragment layouts identical to proj (A: lane=M-row; B: lane=N-col). 24 MFMA/wave.
#define TN 32
__global__ __launch_bounds__(256, 4) void fused_out_kernel(
    const ushort* __restrict__ qbufT, const ushort* __restrict__ vbufT,
    const ushort* __restrict__ gbuf, const float* __restrict__ lam,
    const float* __restrict__ conv_b, float* __restrict__ out) {
    __shared__ ushort Af[12 * 64 * 8];      // [kk*4+hi][v][j], 12288 B
    __shared__ ushort Sf[4][12 * 32 * 8];   // per h: [kk*4+hi][nl][j], 6144 B each

    int b = blockIdx.y;
    int n0 = blockIdx.x * TN;
    int t = threadIdx.x;

    // ---- issue all global loads first ----
    uint4 vld0 = {0, 0, 0, 0}, vld1 = {0, 0, 0, 0};
    {
        int c = t >> 3, vg = t & 7;
        int n = n0 - 11 + c;
        if (n >= 0 && n < Nn)
            vld0 = *reinterpret_cast<const uint4*>(&vbufT[((size_t)b * Nn + n) * 64 + vg * 8]);
        int i2 = t + 256;
        if (i2 < 432) {
            int c2 = i2 >> 3, vg2 = i2 & 7;
            int n2 = n0 - 11 + c2;
            if (n2 >= 0 && n2 < Nn)
                vld1 = *reinterpret_cast<const uint4*>(&vbufT[((size_t)b * Nn + n2) * 64 + vg2 * 8]);
        }
    }
    uint2 gld0, gld1, gld2 = {0, 0};
    {
        int i = t;          // r = i>>5, nl = i&31  (i < 736)
        gld0 = *reinterpret_cast<const uint2*>(
            &gbuf[(((size_t)b * Rr + (i >> 5)) * Nn + n0 + (i & 31)) * 4]);
        int i1 = t + 256;
        gld1 = *reinterpret_cast<const uint2*>(
            &gbuf[(((size_t)b * Rr + (i1 >> 5)) * Nn + n0 + (i1 & 31)) * 4]);
        int i2 = t + 512;
        if (i2 < 736)
            gld2 = *reinterpret_cast<const uint2*>(
                &gbuf[(((size_t)b * Rr + (i2 >> 5)) * Nn + n0 + (i2 & 31)) * 4]);
    }
    uint2 qld0, qld1;
    {
        int i = t;          // k = i>>5, nl = i&31
        qld0 = *reinterpret_cast<const uint2*>(
            &qbufT[((size_t)b * Nn + n0 + (i & 31)) * 64 + (i >> 5) * 4]);
        int i2 = t + 256;
        qld1 = *reinterpret_cast<const uint2*>(
            &qbufT[((size_t)b * Nn + n0 + (i2 & 31)) * 64 + (i2 >> 5) * 4]);
    }
    float4 lcl = *reinterpret_cast<const float4*>(&lam[(size_t)b * Kk * Vv + t * 4]);
    float cb = conv_b[t >> 4];   // k = (t*4)>>6 = t>>4

    // ---- zero-init fragments (NaN-safe for pad regions) ----
    uint4 z4 = {0, 0, 0, 0};
#pragma unroll
    for (int m = 0; m < 3; m++) reinterpret_cast<uint4*>(Af)[t + 256 * m] = z4;
#pragma unroll
    for (int m = 0; m < 6; m++) reinterpret_cast<uint4*>(Sf)[t + 256 * m] = z4;
    __syncthreads();

    // ---- scatter fills ----
    // vv -> A cols 0..53
    {
        int c = t >> 3, vg = t & 7;
        int kk = c >> 5, hi = (c >> 3) & 3, j = c & 7;
        ushort* base = &Af[((kk * 4 + hi) * 64 + vg * 8) * 8 + j];
        uint va[4] = {vld0.x, vld0.y, vld0.z, vld0.w};
#pragma unroll
        for (int e = 0; e < 4; e++) {
            base[(2 * e + 0) * 8] = (ushort)(va[e] & 0xffff);
            base[(2 * e + 1) * 8] = (ushort)(va[e] >> 16);
        }
        int i2 = t + 256;
        if (i2 < 432) {
            int c2 = i2 >> 3, vg2 = i2 & 7;
            int kk2 = c2 >> 5, hi2 = (c2 >> 3) & 3, j2 = c2 & 7;
            ushort* base2 = &Af[((kk2 * 4 + hi2) * 64 + vg2 * 8) * 8 + j2];
            uint vb4[4] = {vld1.x, vld1.y, vld1.z, vld1.w};
#pragma unroll
            for (int e = 0; e < 4; e++) {
                base2[(2 * e + 0) * 8] = (ushort)(vb4[e] & 0xffff);
                base2[(2 * e + 1) * 8] = (ushort)(vb4[e] >> 16);
            }
        }
    }
    // lc -> A cols 54..69
    {
        int k = t >> 4, v0 = (t & 15) * 4;
        int c = 54 + k;
        int kk = c >> 5, hi = (c >> 3) & 3, j = c & 7;
        ushort* base = &Af[((kk * 4 + hi) * 64 + v0) * 8 + j];
        base[0]  = f2bf(lcl.x + cb);
        base[8]  = f2bf(lcl.y + cb);
        base[16] = f2bf(lcl.z + cb);
        base[24] = f2bf(lcl.w + cb);
    }
    // g -> S band rows 0..53
    {
        int i = t;
        {
            int r = i >> 5, nl = i & 31, m = nl + r;
            int kk = m >> 5, hi = (m >> 3) & 3, j = m & 7;
            int off = ((kk * 4 + hi) * 32 + nl) * 8 + j;
            Sf[0][off] = (ushort)(gld0.x & 0xffff);
            Sf[1][off] = (ushort)(gld0.x >> 16);
            Sf[2][off] = (ushort)(gld0.y & 0xffff);
            Sf[3][off] = (ushort)(gld0.y >> 16);
        }
        int i1 = t + 256;
        {
            int r = i1 >> 5, nl = i1 & 31, m = nl + r;
            int kk = m >> 5, hi = (m >> 3) & 3, j = m & 7;
            int off = ((kk * 4 + hi) * 32 + nl) * 8 + j;
            Sf[0][off] = (ushort)(gld1.x & 0xffff);
            Sf[1][off] = (ushort)(gld1.x >> 16);
            Sf[2][off] = (ushort)(gld1.y & 0xffff);
            Sf[3][off] = (ushort)(gld1.y >> 16);
        }
        int i2 = t + 512;
        if (i2 < 736) {
            int r = i2 >> 5, nl = i2 & 31, m = nl + r;
            int kk = m >> 5, hi = (m >> 3) & 3, j = m & 7;
            int off = ((kk * 4 + hi) * 32 + nl) * 8 + j;
            Sf[0][off] = (ushort)(gld2.x & 0xffff);
            Sf[1][off] = (ushort)(gld2.x >> 16);
            Sf[2][off] = (ushort)(gld2.y & 0xffff);
            Sf[3][off] = (ushort)(gld2.y >> 16);
        }
    }
    // q -> S rows 54..69
    {
        int i = t;
        {
            int k = i >> 5, nl = i & 31, m = 54 + k;
            int kk = m >> 5, hi = (m >> 3) & 3, j = m & 7;
            int off = ((kk * 4 + hi) * 32 + nl) * 8 + j;
            Sf[0][off] = (ushort)(qld0.x & 0xffff);
            Sf[1][off] = (ushort)(qld0.x >> 16);
            Sf[2][off] = (ushort)(qld0.y & 0xffff);
            Sf[3][off] = (ushort)(qld0.y >> 16);
        }
        int i2 = t + 256;
        {
            int k = i2 >> 5, nl = i2 & 31, m = 54 + k;
            int kk = m >> 5, hi = (m >> 3) & 3, j = m & 7;
            int off = ((kk * 4 + hi) * 32 + nl) * 8 + j;
            Sf[0][off] = (ushort)(qld1.x & 0xffff);
            Sf[1][off] = (ushort)(qld1.x >> 16);
            Sf[2][off] = (ushort)(qld1.y & 0xffff);
            Sf[3][off] = (ushort)(qld1.y >> 16);
        }
    }
    __syncthreads();

    // ---- MFMA compute: wave = h ----
    int h = t >> 6, l = t & 63;
    int lm = l & 15, hif = l >> 4;

    f32x4 acc[4][2];
#pragma unroll
    for (int mt = 0; mt < 4; mt++)
#pragma unroll
        for (int nt = 0; nt < 2; nt++) acc[mt][nt] = (f32x4){0.f, 0.f, 0.f, 0.f};

#pragma unroll
    for (int kk = 0; kk < 3; kk++) {
        bf16x8s bfr[2];
#pragma unroll
        for (int nt = 0; nt < 2; nt++)
            bfr[nt] = *reinterpret_cast<const bf16x8s*>(
                &Sf[h][((kk * 4 + hif) * 32 + nt * 16 + lm) * 8]);
#pragma unroll
        for (int mt = 0; mt < 4; mt++) {
            bf16x8s afr = *reinterpret_cast<const bf16x8s*>(
                &Af[((kk * 4 + hif) * 64 + mt * 16 + lm) * 8]);
#pragma unroll
            for (int nt = 0; nt < 2; nt++)
                acc[mt][nt] = __builtin_amdgcn_mfma_f32_16x16x32_bf16(afr, bfr[nt], acc[mt][nt], 0, 0, 0);
        }
    }

    // ---- store: C layout col=lane&15 (n), row=(lane>>4)*4+reg (v) ----
    float* ob = out + ((size_t)b * 256 + h * 64) * Nn + n0;
#pragma unroll
    for (int mt = 0; mt < 4; mt++)
#pragma unroll
        for (int nt = 0; nt < 2; nt++)
#pragma unroll
            for (int rr = 0; rr < 4; rr++) {
                int v = mt * 16 + hif * 4 + rr;
                ob[(size_t)v * Nn + nt * 16 + lm] = acc[mt][nt][rr];
            }
}

extern "C" void kernel_launch(void* const* d_in, const int* in_sizes, int n_in,
                              void* d_out, int out_size, void* d_ws, size_t ws_size,
                              hipStream_t stream) {
    const float* x      = (const float*)d_in[0];
    const float* Wq     = (const float*)d_in[1];
    const float* qg     = (const float*)d_in[2];
    const float* qb     = (const float*)d_in[3];
    const float* qm     = (const float*)d_in[4];
    const float* qv     = (const float*)d_in[5];
    const float* Wk     = (const float*)d_in[6];
    const float* Wv     = (const float*)d_in[7];
    const float* vg     = (const float*)d_in[8];
    const float* vb     = (const float*)d_in[9];
    const float* vm     = (const float*)d_in[10];
    const float* vvar   = (const float*)d_in[11];
    const float* conv_w = (const float*)d_in[12];
    const float* conv_b = (const float*)d_in[13];
    float* out = (float*)d_out;

    float* wsf = (float*)d_ws;
    ushort* Wf16  = (ushort*)wsf;                       // 36864 u16 = 18432 f
    float*  bias  = wsf + 18432;                        // 256 f
    float*  kbuf  = wsf + 18688;                        // 16*16*4096 = 1048576 f
    float*  lam   = wsf + 1067264;                      // 16384 f
    ushort* qbufT = (ushort*)(wsf + 1083648);           // 16*4096*64 u16 = 2097152 f
    ushort* vbufT = (ushort*)(wsf + 3180800);           // 16*4096*64 u16 = 2097152 f
    ushort* gbuf  = (ushort*)(wsf + 5277952);           // 16*23*4096*4 u16 = 3014656 f

    pack_kernel<<<Cc, 256, 0, stream>>>(Wq, qg, qb, qm, qv, Wk, Wv, vg, vb, vm, vvar,
                                        Wf16, bias);
    proj_mfma_kernel<<<dim3(Nn / 64, Bn), 256, 0, stream>>>(x, Wf16, bias,
                                                            qbufT, kbuf, vbufT);
    g_kernel<<<dim3(Nn / 256, Bn), 256, 0, stream>>>(qbufT, conv_w, gbuf, lam);
    softmax_kernel<<<dim3(Kk, Bn), 256, 0, stream>>>(kbuf);
    lamc_kernel<<<dim3(Nn / NCHUNK, Bn), 256, 0, stream>>>(kbuf, vbufT, lam);
    fused_out_kernel<<<dim3(Nn / TN, Bn), 256, 0, stream>>>(qbufT, vbufT, gbuf, lam,
                                                            conv_b, out);
}

// Round 20
// 63.538 us; speedup vs baseline: 7.0460x; 1.0550x over previous
//
#include <hip/hip_runtime.h>
#include <hip/hip_bf16.h>

typedef unsigned int uint;
typedef unsigned short ushort;

// Dims
#define Bn 16
#define Dd 256
#define Nn 4096
#define Hh 4
#define Kk 16
#define Vv 64
#define Rr 23
#define Cc 144   // 64 q + 16 k + 64 v
#define NRT 9    // 144/16 row-tiles

typedef short bf16x8s __attribute__((ext_vector_type(8)));
typedef float f32x4 __attribute__((ext_vector_type(4)));

static __device__ __forceinline__ ushort f2bf(float f) {
    __hip_bfloat16 h = __float2bfloat16(f);
    return __builtin_bit_cast(ushort, h);
}
static __device__ __forceinline__ float bf2f(ushort u) {
    return __uint_as_float(((uint)u) << 16);
}
static __device__ __forceinline__ float bflo(uint u) { return __uint_as_float(u << 16); }
static __device__ __forceinline__ float bfhi(uint u) { return __uint_as_float(u & 0xffff0000u); }

// ---------------- Kernel 1: pack 144 BN-folded rows (bf16, A-fragment order) ----------------
__global__ __launch_bounds__(256) void pack_kernel(
    const float* __restrict__ Wq, const float* __restrict__ qg, const float* __restrict__ qb,
    const float* __restrict__ qm, const float* __restrict__ qv,
    const float* __restrict__ Wk, const float* __restrict__ Wv,
    const float* __restrict__ vg, const float* __restrict__ vb,
    const float* __restrict__ vm, const float* __restrict__ vvar,
    ushort* __restrict__ Wf16, float* __restrict__ bias) {
    int c = blockIdx.x;       // 0..143
    int d = threadIdx.x;      // 0..255
    float scale, bs;
    const float* src;
    if (c < 64) {
        scale = qg[c] * rsqrtf(qv[c] + 1e-5f);
        bs = qb[c] - qm[c] * scale;
        src = Wq + c * Dd;
    } else if (c < 80) {
        scale = 1.f; bs = 0.f;
        src = Wk + (c - 64) * Dd;
    } else {
        int j = c - 80;
        scale = vg[j] * rsqrtf(vvar[j] + 1e-5f);
        bs = vb[j] - vm[j] * scale;
        src = Wv + j * Dd;
    }
    int rt = c >> 4, lm = c & 15;
    int kk = d >> 5, hi = (d >> 3) & 3, j = d & 7;
    Wf16[((rt * 8 + kk) * 64 + hi * 16 + lm) * 8 + j] = f2bf(src[d] * scale);
    if (d == 0) bias[c] = bs;
}

// ---------------- Kernel 2: MFMA projection -> consumer-layout buffers (R14 version) ---------
__global__ __launch_bounds__(256, 4) void proj_mfma_kernel(
    const float* __restrict__ x, const ushort* __restrict__ Wf16,
    const float* __restrict__ bias,
    ushort* __restrict__ qbufT, float* __restrict__ kbuf,
    ushort* __restrict__ vbufT) {
    __shared__ ushort Wlds[NRT * 2 * 64 * 8];   // 18432 B (2 k-steps per phase)

    int b = blockIdx.y;
    int n0 = blockIdx.x * 64;
    int t = threadIdx.x;
    int w = t >> 6, l = t & 63;
    int lm = l & 15, hi = l >> 4;
    int n = n0 + w * 16 + lm;     // this lane's output column

    const uint* WfU = (const uint*)Wf16;
    uint* WldsU = (uint*)Wlds;

    f32x4 acc[NRT];
#pragma unroll
    for (int rt = 0; rt < NRT; rt++) acc[rt] = (f32x4){0.f, 0.f, 0.f, 0.f};

    const float* xb = x + (size_t)b * Dd * Nn + n;

#pragma unroll
    for (int p = 0; p < 4; p++) {
        int kb = p * 2;
        if (p) __syncthreads();
#pragma unroll
        for (int i = 0; i < 18; i++) {
            int flat = t + 256 * i;
            int f2 = flat >> 8;          // rt*2 + kkl
            int rt = f2 >> 1, kkl = f2 & 1;
            WldsU[flat] = WfU[((rt * 8 + kb + kkl) << 8) + (flat & 255)];
        }
        __syncthreads();

#pragma unroll
        for (int kkl = 0; kkl < 2; kkl++) {
            int kk = kb + kkl;
            const float* xp = xb + (size_t)(kk * 32 + hi * 8) * Nn;
            float f[8];
#pragma unroll
            for (int j = 0; j < 8; j++) f[j] = xp[(size_t)j * Nn];
            bf16x8s bfrag;
#pragma unroll
            for (int j = 0; j < 8; j++) bfrag[j] = (short)f2bf(f[j]);
#pragma unroll
            for (int rt = 0; rt < NRT; rt++) {
                bf16x8s afrag = *reinterpret_cast<const bf16x8s*>(
                    &Wlds[(size_t)((rt * 2 + kkl) * 64 + l) * 8]);
                acc[rt] = __builtin_amdgcn_mfma_f32_16x16x32_bf16(afrag, bfrag, acc[rt], 0, 0, 0);
            }
        }
    }

    // ---- epilogue ----
#pragma unroll
    for (int rr = 0; rr < 4; rr++) {
        int kc = hi * 4 + rr;
        kbuf[((size_t)b * 16 + kc) * Nn + n] = acc[4][rr] + bias[64 + kc];
    }

    __syncthreads();   // done reading Wlds; reuse as transpose buffer (exactly 18432 B)
    {
        int nl = w * 16 + lm;
#pragma unroll
        for (int rt = 0; rt < 4; rt++)
#pragma unroll
            for (int rr = 0; rr < 4; rr++) {
                int kq = hi * 4 + rr;
                Wlds[nl * 72 + kq * 4 + rt] = f2bf(acc[rt][rr] + bias[rt * 16 + kq]);
            }
#pragma unroll
        for (int rt = 5; rt < 9; rt++)
#pragma unroll
            for (int rr = 0; rr < 4; rr++) {
                int v = (rt - 5) * 16 + hi * 4 + rr;
                Wlds[4608 + nl * 72 + v] = f2bf(acc[rt][rr] + bias[80 + v]);
            }
    }
    __syncthreads();

#pragma unroll
    for (int m = 0; m < 2; m++) {
        int i = t + 256 * m;
        int row = i >> 3, seg = i & 7;
        uint4 u = *reinterpret_cast<const uint4*>(&Wlds[row * 72 + seg * 8]);
        *reinterpret_cast<uint4*>(&qbufT[((size_t)b * Nn + n0 + row) * 64 + seg * 8]) = u;
    }
#pragma unroll
    for (int m = 0; m < 2; m++) {
        int i = t + 256 * m;
        int row = i >> 3, seg = i & 7;
        uint4 u = *reinterpret_cast<const uint4*>(&Wlds[4608 + row * 72 + seg * 8]);
        *reinterpret_cast<uint4*>(&vbufT[((size_t)b * Nn + n0 + row) * 64 + seg * 8]) = u;
    }
}

// ---------------- Kernel 2b: g_kernel — gbuf + zero num/den ----------------
__global__ __launch_bounds__(256) void g_kernel(
    const ushort* __restrict__ qbufT, const float* __restrict__ conv_w,
    ushort* __restrict__ gbuf, float* __restrict__ num, float* __restrict__ den) {
    __shared__ float cws[Kk][24];   // [k][r], padded
    int b = blockIdx.y;
    int n = blockIdx.x * 256 + threadIdx.x;
    int t = threadIdx.x;
    for (int i = t; i < Kk * Rr; i += 256) cws[i / Rr][i % Rr] = conv_w[i];
    if (blockIdx.x == 0) {
        float4 z = {0.f, 0.f, 0.f, 0.f};
        *reinterpret_cast<float4*>(&num[(size_t)b * Kk * Vv + t * 4]) = z;
        if (t < 4) *reinterpret_cast<float4*>(&den[(size_t)b * Kk + t * 4]) = z;
    }
    __syncthreads();

    float qf[16][4];
    const uint4* qp = reinterpret_cast<const uint4*>(&qbufT[((size_t)b * Nn + n) * 64]);
#pragma unroll
    for (int m = 0; m < 8; m++) {
        uint4 u = qp[m];
        uint vals[4] = {u.x, u.y, u.z, u.w};
#pragma unroll
        for (int j = 0; j < 4; j++) {
            int idx = m * 8 + j * 2;        // = k*4 + h, h even
            int k = idx >> 2, h = idx & 3;
            qf[k][h]     = bflo(vals[j]);
            qf[k][h + 1] = bfhi(vals[j]);
        }
    }

#pragma unroll
    for (int r = 0; r < Rr; r++) {
        float g0 = 0.f, g1 = 0.f, g2 = 0.f, g3 = 0.f;
#pragma unroll
        for (int k = 0; k < 16; k++) {
            float c = cws[k][r];
            g0 += qf[k][0] * c;
            g1 += qf[k][1] * c;
            g2 += qf[k][2] * c;
            g3 += qf[k][3] * c;
        }
        uint2 o;
        o.x = ((uint)f2bf(g1) << 16) | (uint)f2bf(g0);
        o.y = ((uint)f2bf(g3) << 16) | (uint)f2bf(g2);
        *reinterpret_cast<uint2*>(&gbuf[(((size_t)b * Rr + r) * Nn + n) * 4]) = o;
    }
}

// ---------------- Kernel 4: fused exp-softmax + lam contraction ----------------
// num[k][v] += sum_n e^{k[n]} * vv[v][n];  den[k] += sum_n e^{k[n]}   (normalized in fused)
#define NCHUNK 128
__global__ __launch_bounds__(256) void lamc_kernel(
    const float* __restrict__ kbuf, const ushort* __restrict__ vbufT,
    float* __restrict__ num, float* __restrict__ den) {
    int b = blockIdx.y;
    int n0 = blockIdx.x * NCHUNK;
    __shared__ float kks[Kk][NCHUNK + 1];   // holds exp(scores); 8256 B
    __shared__ ushort vvT[NCHUNK][72];      // 18432 B, rows 144 B
    __shared__ float dpart[Kk][32];         // 2048 B
    int t = threadIdx.x;
#pragma unroll
    for (int m = 0; m < 2; m++) {
        int i = t + 256 * m;
        int r = i >> 5, seg = i & 31;
        float4 f = *reinterpret_cast<const float4*>(&kbuf[((size_t)b * 16 + r) * Nn + n0 + seg * 4]);
        float e0 = __expf(f.x), e1 = __expf(f.y), e2 = __expf(f.z), e3 = __expf(f.w);
        kks[r][seg * 4 + 0] = e0;
        kks[r][seg * 4 + 1] = e1;
        kks[r][seg * 4 + 2] = e2;
        kks[r][seg * 4 + 3] = e3;
        dpart[r][seg] = e0 + e1 + e2 + e3;   // covers all (r,seg) exactly once over m=0,1
    }
#pragma unroll
    for (int m = 0; m < 4; m++) {
        int i = t + 256 * m;
        int row = i >> 3, seg = i & 7;
        uint4 u = *reinterpret_cast<const uint4*>(&vbufT[((size_t)b * Nn + n0 + row) * 64 + seg * 8]);
        *reinterpret_cast<uint4*>(&vvT[row][seg * 8]) = u;
    }
    __syncthreads();
    int v = t & 63, k0 = t >> 6;
    float acc4[4] = {0.f, 0.f, 0.f, 0.f};
    for (int nl = 0; nl < NCHUNK; nl++) {
        float wv = bf2f(vvT[nl][v]);
#pragma unroll
        for (int j2 = 0; j2 < 4; j2++) acc4[j2] += kks[k0 + 4 * j2][nl] * wv;
    }
#pragma unroll
    for (int j2 = 0; j2 < 4; j2++)
        atomicAdd(&num[((size_t)b * Kk + k0 + 4 * j2) * Vv + v], acc4[j2]);
    // den partials: 16 threads reduce 32 each
    if (t < Kk) {
        float s = 0.f;
#pragma unroll
        for (int seg = 0; seg < 32; seg++) s += dpart[t][seg];
        atomicAdd(&den[(size_t)b * Kk + t], s);
    }
}

// ---------------- Kernel 5: fused output via MFMA (R19 + den normalization) ----------------
#define TN 32
__global__ __launch_bounds__(256, 4) void fused_out_kernel(
    const ushort* __restrict__ qbufT, const ushort* __restrict__ vbufT,
    const ushort* __restrict__ gbuf, const float* __restrict__ num,
    const float* __restrict__ den, const float* __restrict__ conv_b,
    float* __restrict__ out) {
    __shared__ ushort Af[12 * 64 * 8];      // [kk*4+hi][v][j], 12288 B
    __shared__ ushort Sf[4][12 * 32 * 8];   // per h: [kk*4+hi][nl][j], 6144 B each

    int b = blockIdx.y;
    int n0 = blockIdx.x * TN;
    int t = threadIdx.x;

    // ---- issue all global loads first ----
    uint4 vld0 = {0, 0, 0, 0}, vld1 = {0, 0, 0, 0};
    {
        int c = t >> 3, vg = t & 7;
        int n = n0 - 11 + c;
        if (n >= 0 && n < Nn)
            vld0 = *reinterpret_cast<const uint4*>(&vbufT[((size_t)b * Nn + n) * 64 + vg * 8]);
        int i2 = t + 256;
        if (i2 < 432) {
            int c2 = i2 >> 3, vg2 = i2 & 7;
            int n2 = n0 - 11 + c2;
            if (n2 >= 0 && n2 < Nn)
                vld1 = *reinterpret_cast<const uint4*>(&vbufT[((size_t)b * Nn + n2) * 64 + vg2 * 8]);
        }
    }
    uint2 gld0, gld1, gld2 = {0, 0};
    {
        int i = t;          // r = i>>5, nl = i&31  (i < 736)
        gld0 = *reinterpret_cast<const uint2*>(
            &gbuf[(((size_t)b * Rr + (i >> 5)) * Nn + n0 + (i & 31)) * 4]);
        int i1 = t + 256;
        gld1 = *reinterpret_cast<const uint2*>(
            &gbuf[(((size_t)b * Rr + (i1 >> 5)) * Nn + n0 + (i1 & 31)) * 4]);
        int i2 = t + 512;
        if (i2 < 736)
            gld2 = *reinterpret_cast<const uint2*>(
                &gbuf[(((size_t)b * Rr + (i2 >> 5)) * Nn + n0 + (i2 & 31)) * 4]);
    }
    uint2 qld0, qld1;
    {
        int i = t;          // k = i>>5, nl = i&31
        qld0 = *reinterpret_cast<const uint2*>(
            &qbufT[((size_t)b * Nn + n0 + (i & 31)) * 64 + (i >> 5) * 4]);
        int i2 = t + 256;
        qld1 = *reinterpret_cast<const uint2*>(
            &qbufT[((size_t)b * Nn + n0 + (i2 & 31)) * 64 + (i2 >> 5) * 4]);
    }
    float4 lcl = *reinterpret_cast<const float4*>(&num[(size_t)b * Kk * Vv + t * 4]);
    float dk = den[(size_t)b * Kk + (t >> 4)];   // k = t>>4 for this thread's 4 v's
    float cb = conv_b[t >> 4];

    // ---- zero-init fragments (NaN-safe for pad regions) ----
    uint4 z4 = {0, 0, 0, 0};
#pragma unroll
    for (int m = 0; m < 3; m++) reinterpret_cast<uint4*>(Af)[t + 256 * m] = z4;
#pragma unroll
    for (int m = 0; m < 6; m++) reinterpret_cast<uint4*>(Sf)[t + 256 * m] = z4;
    __syncthreads();

    // ---- scatter fills ----
    // vv -> A cols 0..53
    {
        int c = t >> 3, vg = t & 7;
        int kk = c >> 5, hi = (c >> 3) & 3, j = c & 7;
        ushort* base = &Af[((kk * 4 + hi) * 64 + vg * 8) * 8 + j];
        uint va[4] = {vld0.x, vld0.y, vld0.z, vld0.w};
#pragma unroll
        for (int e = 0; e < 4; e++) {
            base[(2 * e + 0) * 8] = (ushort)(va[e] & 0xffff);
            base[(2 * e + 1) * 8] = (ushort)(va[e] >> 16);
        }
        int i2 = t + 256;
        if (i2 < 432) {
            int c2 = i2 >> 3, vg2 = i2 & 7;
            int kk2 = c2 >> 5, hi2 = (c2 >> 3) & 3, j2 = c2 & 7;
            ushort* base2 = &Af[((kk2 * 4 + hi2) * 64 + vg2 * 8) * 8 + j2];
            uint vb4[4] = {vld1.x, vld1.y, vld1.z, vld1.w};
#pragma unroll
            for (int e = 0; e < 4; e++) {
                base2[(2 * e + 0) * 8] = (ushort)(vb4[e] & 0xffff);
                base2[(2 * e + 1) * 8] = (ushort)(vb4[e] >> 16);
            }
        }
    }
    // lc = num/den + cb -> A cols 54..69
    {
        int k = t >> 4, v0 = (t & 15) * 4;
        int c = 54 + k;
        int kk = c >> 5, hi = (c >> 3) & 3, j = c & 7;
        ushort* base = &Af[((kk * 4 + hi) * 64 + v0) * 8 + j];
        float inv = 1.f / dk;
        base[0]  = f2bf(lcl.x * inv + cb);
        base[8]  = f2bf(lcl.y * inv + cb);
        base[16] = f2bf(lcl.z * inv + cb);
        base[24] = f2bf(lcl.w * inv + cb);
    }
    // g -> S band rows 0..53
    {
        int i = t;
        {
            int r = i >> 5, nl = i & 31, m = nl + r;
            int kk = m >> 5, hi = (m >> 3) & 3, j = m & 7;
            int off = ((kk * 4 + hi) * 32 + nl) * 8 + j;
            Sf[0][off] = (ushort)(gld0.x & 0xffff);
            Sf[1][off] = (ushort)(gld0.x >> 16);
            Sf[2][off] = (ushort)(gld0.y & 0xffff);
            Sf[3][off] = (ushort)(gld0.y >> 16);
        }
        int i1 = t + 256;
        {
            int r = i1 >> 5, nl = i1 & 31, m = nl + r;
            int kk = m >> 5, hi = (m >> 3) & 3, j = m & 7;
            int off = ((kk * 4 + hi) * 32 + nl) * 8 + j;
            Sf[0][off] = (ushort)(gld1.x & 0xffff);
            Sf[1][off] = (ushort)(gld1.x >> 16);
            Sf[2][off] = (ushort)(gld1.y & 0xffff);
            Sf[3][off] = (ushort)(gld1.y >> 16);
        }
        int i2 = t + 512;
        if (i2 < 736) {
            int r = i2 >> 5, nl = i2 & 31, m = nl + r;
            int kk = m >> 5, hi = (m >> 3) & 3, j = m & 7;
            int off = ((kk * 4 + hi) * 32 + nl) * 8 + j;
            Sf[0][off] = (ushort)(gld2.x & 0xffff);
            Sf[1][off] = (ushort)(gld2.x >> 16);
            Sf[2][off] = (ushort)(gld2.y & 0xffff);
            Sf[3][off] = (ushort)(gld2.y >> 16);
        }
    }
    // q -> S rows 54..69
    {
        int i = t;
        {
            int k = i >> 5, nl = i & 31, m = 54 + k;
            int kk = m >> 5, hi = (m >> 3) & 3, j = m & 7;
            int off = ((kk * 4 + hi) * 32 + nl) * 8 + j;
            Sf[0][off] = (ushort)(qld0.x & 0xffff);
            Sf[1][off] = (ushort)(qld0.x >> 16);
            Sf[2][off] = (ushort)(qld0.y & 0xffff);
            Sf[3][off] = (ushort)(qld0.y >> 16);
        }
        int i2 = t + 256;
        {
            int k = i2 >> 5, nl = i2 & 31, m = 54 + k;
            int kk = m >> 5, hi = (m >> 3) & 3, j = m & 7;
            int off = ((kk * 4 + hi) * 32 + nl) * 8 + j;
            Sf[0][off] = (ushort)(qld1.x & 0xffff);
            Sf[1][off] = (ushort)(qld1.x >> 16);
            Sf[2][off] = (ushort)(qld1.y & 0xffff);
            Sf[3][off] = (ushort)(qld1.y >> 16);
        }
    }
    __syncthreads();

    // ---- MFMA compute: wave = h ----
    int h = t >> 6, l = t & 63;
    int lm = l & 15, hif = l >> 4;

    f32x4 acc[4][2];
#pragma unroll
    for (int mt = 0; mt < 4; mt++)
#pragma unroll
        for (int nt = 0; nt < 2; nt++) acc[mt][nt] = (f32x4){0.f, 0.f, 0.f, 0.f};

#pragma unroll
    for (int kk = 0; kk < 3; kk++) {
        bf16x8s bfr[2];
#pragma unroll
        for (int nt = 0; nt < 2; nt++)
            bfr[nt] = *reinterpret_cast<const bf16x8s*>(
                &Sf[h][((kk * 4 + hif) * 32 + nt * 16 + lm) * 8]);
#pragma unroll
        for (int mt = 0; mt < 4; mt++) {
            bf16x8s afr = *reinterpret_cast<const bf16x8s*>(
                &Af[((kk * 4 + hif) * 64 + mt * 16 + lm) * 8]);
#pragma unroll
            for (int nt = 0; nt < 2; nt++)
                acc[mt][nt] = __builtin_amdgcn_mfma_f32_16x16x32_bf16(afr, bfr[nt], acc[mt][nt], 0, 0, 0);
        }
    }

    // ---- store: C layout col=lane&15 (n), row=(lane>>4)*4+reg (v) ----
    float* ob = out + ((size_t)b * 256 + h * 64) * Nn + n0;
#pragma unroll
    for (int mt = 0; mt < 4; mt++)
#pragma unroll
        for (int nt = 0; nt < 2; nt++)
#pragma unroll
            for (int rr = 0; rr < 4; rr++) {
                int v = mt * 16 + hif * 4 + rr;
                ob[(size_t)v * Nn + nt * 16 + lm] = acc[mt][nt][rr];
            }
}

extern "C" void kernel_launch(void* const* d_in, const int* in_sizes, int n_in,
                              void* d_out, int out_size, void* d_ws, size_t ws_size,
                              hipStream_t stream) {
    const float* x      = (const float*)d_in[0];
    const float* Wq     = (const float*)d_in[1];
    const float* qg     = (const float*)d_in[2];
    const float* qb     = (const float*)d_in[3];
    const float* qm     = (const float*)d_in[4];
    const float* qv     = (const float*)d_in[5];
    const float* Wk     = (const float*)d_in[6];
    const float* Wv     = (const float*)d_in[7];
    const float* vg     = (const float*)d_in[8];
    const float* vb     = (const float*)d_in[9];
    const float* vm     = (const float*)d_in[10];
    const float* vvar   = (const float*)d_in[11];
    const float* conv_w = (const float*)d_in[12];
    const float* conv_b = (const float*)d_in[13];
    float* out = (float*)d_out;

    float* wsf = (float*)d_ws;
    ushort* Wf16  = (ushort*)wsf;                       // 36864 u16 = 18432 f
    float*  bias  = wsf + 18432;                        // 256 f
    float*  kbuf  = wsf + 18688;                        // 16*16*4096 = 1048576 f
    float*  num   = wsf + 1067264;                      // 16*1024 = 16384 f
    float*  den   = wsf + 1083648;                      // 16*16 = 256 f
    ushort* qbufT = (ushort*)(wsf + 1083904);           // 16*4096*64 u16 = 2097152 f
    ushort* vbufT = (ushort*)(wsf + 3181056);           // 16*4096*64 u16 = 2097152 f
    ushort* gbuf  = (ushort*)(wsf + 5278208);           // 16*23*4096*4 u16 = 3014656 f

    pack_kernel<<<Cc, 256, 0, stream>>>(Wq, qg, qb, qm, qv, Wk, Wv, vg, vb, vm, vvar,
                                        Wf16, bias);
    proj_mfma_kernel<<<dim3(Nn / 64, Bn), 256, 0, stream>>>(x, Wf16, bias,
                                                            qbufT, kbuf, vbufT);
    g_kernel<<<dim3(Nn / 256, Bn), 256, 0, stream>>>(qbufT, conv_w, gbuf, num, den);
    lamc_kernel<<<dim3(Nn / NCHUNK, Bn), 256, 0, stream>>>(kbuf, vbufT, num, den);
    fused_out_kernel<<<dim3(Nn / TN, Bn), 256, 0, stream>>>(qbufT, vbufT, gbuf, num, den,
                                                            conv_b, out);
}

// Round 22
// 55.397 us; speedup vs baseline: 8.0815x; 1.1470x over previous
//
#include <hip/hip_runtime.h>
#include <hip/hip_bf16.h>

typedef unsigned int uint;
typedef unsigned short ushort;

// Dims
#define Bn 16
#define Dd 256
#define Nn 4096
#define Hh 4
#define Kk 16
#define Vv 64
#define Rr 23
#define Cc 144   // 64 q + 16 k + 64 v
#define NRT 9    // 144/16 row-tiles

typedef short bf16x8s __attribute__((ext_vector_type(8)));
typedef float f32x4 __attribute__((ext_vector_type(4)));

static __device__ __forceinline__ ushort f2bf(float f) {
    __hip_bfloat16 h = __float2bfloat16(f);
    return __builtin_bit_cast(ushort, h);
}
static __device__ __forceinline__ float bf2f(ushort u) {
    return __uint_as_float(((uint)u) << 16);
}
static __device__ __forceinline__ float bflo(uint u) { return __uint_as_float(u << 16); }
static __device__ __forceinline__ float bfhi(uint u) { return __uint_as_float(u & 0xffff0000u); }

// ---------------- Kernel 1: pack weights + cw fragments + zero num/den ----------------
__global__ __launch_bounds__(256) void pack_kernel(
    const float* __restrict__ Wq, const float* __restrict__ qg, const float* __restrict__ qb,
    const float* __restrict__ qm, const float* __restrict__ qv,
    const float* __restrict__ Wk, const float* __restrict__ Wv,
    const float* __restrict__ vg, const float* __restrict__ vb,
    const float* __restrict__ vm, const float* __restrict__ vvar,
    const float* __restrict__ conv_w,
    ushort* __restrict__ Wf16, float* __restrict__ bias,
    ushort* __restrict__ cwf, float* __restrict__ num, float* __restrict__ den) {
    int c = blockIdx.x;       // 0..143
    int t = threadIdx.x;      // 0..255
    int d = t;
    float scale, bs;
    const float* src;
    if (c < 64) {
        scale = qg[c] * rsqrtf(qv[c] + 1e-5f);
        bs = qb[c] - qm[c] * scale;
        src = Wq + c * Dd;
    } else if (c < 80) {
        scale = 1.f; bs = 0.f;
        src = Wk + (c - 64) * Dd;
    } else {
        int j = c - 80;
        scale = vg[j] * rsqrtf(vvar[j] + 1e-5f);
        bs = vb[j] - vm[j] * scale;
        src = Wv + j * Dd;
    }
    int rt = c >> 4, lm = c & 15;
    int kk = d >> 5, hi = (d >> 3) & 3, j = d & 7;
    Wf16[((rt * 8 + kk) * 64 + hi * 16 + lm) * 8 + j] = f2bf(src[d] * scale);
    if (d == 0) bias[c] = bs;

    // block 0: cw^T A-fragments. FIXED layout: tile stride 512 (64 lanes x 8 elems).
    // flat = mt*512 + l*8 + jj ; lane l: row r = mt*16 + (l&15), k = (l>>4)*8 + jj (0..31).
    if (c == 0) {
#pragma unroll
        for (int m = 0; m < 4; m++) {
            int flat = t + 256 * m;           // 0..1023
            int mt = flat >> 9, rem = flat & 511;
            int l = rem >> 3, jj = rem & 7;
            int r = mt * 16 + (l & 15);
            int k = (l >> 4) * 8 + jj;
            float v = (r < Rr && k < Kk) ? conv_w[k * Rr + r] : 0.f;
            cwf[flat] = f2bf(v);
        }
    }
    // block 1: zero num (16384 f) and den (256 f)
    if (c == 1) {
        float4 z = {0.f, 0.f, 0.f, 0.f};
#pragma unroll
        for (int m = 0; m < 16; m++)
            reinterpret_cast<float4*>(num)[t + 256 * m] = z;
        if (t < 64) reinterpret_cast<float4*>(den)[t] = z;
    }
}

// ---------------- Kernel 2: MFMA projection -> consumer-layout buffers (R14 version) ---------
__global__ __launch_bounds__(256, 4) void proj_mfma_kernel(
    const float* __restrict__ x, const ushort* __restrict__ Wf16,
    const float* __restrict__ bias,
    ushort* __restrict__ qbufT, float* __restrict__ kbuf,
    ushort* __restrict__ vbufT) {
    __shared__ ushort Wlds[NRT * 2 * 64 * 8];   // 18432 B (2 k-steps per phase)

    int b = blockIdx.y;
    int n0 = blockIdx.x * 64;
    int t = threadIdx.x;
    int w = t >> 6, l = t & 63;
    int lm = l & 15, hi = l >> 4;
    int n = n0 + w * 16 + lm;     // this lane's output column

    const uint* WfU = (const uint*)Wf16;
    uint* WldsU = (uint*)Wlds;

    f32x4 acc[NRT];
#pragma unroll
    for (int rt = 0; rt < NRT; rt++) acc[rt] = (f32x4){0.f, 0.f, 0.f, 0.f};

    const float* xb = x + (size_t)b * Dd * Nn + n;

#pragma unroll
    for (int p = 0; p < 4; p++) {
        int kb = p * 2;
        if (p) __syncthreads();
#pragma unroll
        for (int i = 0; i < 18; i++) {
            int flat = t + 256 * i;
            int f2 = flat >> 8;          // rt*2 + kkl
            int rt = f2 >> 1, kkl = f2 & 1;
            WldsU[flat] = WfU[((rt * 8 + kb + kkl) << 8) + (flat & 255)];
        }
        __syncthreads();

#pragma unroll
        for (int kkl = 0; kkl < 2; kkl++) {
            int kk = kb + kkl;
            const float* xp = xb + (size_t)(kk * 32 + hi * 8) * Nn;
            float f[8];
#pragma unroll
            for (int j = 0; j < 8; j++) f[j] = xp[(size_t)j * Nn];
            bf16x8s bfrag;
#pragma unroll
            for (int j = 0; j < 8; j++) bfrag[j] = (short)f2bf(f[j]);
#pragma unroll
            for (int rt = 0; rt < NRT; rt++) {
                bf16x8s afrag = *reinterpret_cast<const bf16x8s*>(
                    &Wlds[(size_t)((rt * 2 + kkl) * 64 + l) * 8]);
                acc[rt] = __builtin_amdgcn_mfma_f32_16x16x32_bf16(afrag, bfrag, acc[rt], 0, 0, 0);
            }
        }
    }

    // ---- epilogue ----
#pragma unroll
    for (int rr = 0; rr < 4; rr++) {
        int kc = hi * 4 + rr;
        kbuf[((size_t)b * 16 + kc) * Nn + n] = acc[4][rr] + bias[64 + kc];
    }

    __syncthreads();   // done reading Wlds; reuse as transpose buffer (exactly 18432 B)
    {
        int nl = w * 16 + lm;
#pragma unroll
        for (int rt = 0; rt < 4; rt++)
#pragma unroll
            for (int rr = 0; rr < 4; rr++) {
                int kq = hi * 4 + rr;
                Wlds[nl * 72 + kq * 4 + rt] = f2bf(acc[rt][rr] + bias[rt * 16 + kq]);
            }
#pragma unroll
        for (int rt = 5; rt < 9; rt++)
#pragma unroll
            for (int rr = 0; rr < 4; rr++) {
                int v = (rt - 5) * 16 + hi * 4 + rr;
                Wlds[4608 + nl * 72 + v] = f2bf(acc[rt][rr] + bias[80 + v]);
            }
    }
    __syncthreads();

#pragma unroll
    for (int m = 0; m < 2; m++) {
        int i = t + 256 * m;
        int row = i >> 3, seg = i & 7;
        uint4 u = *reinterpret_cast<const uint4*>(&Wlds[row * 72 + seg * 8]);
        *reinterpret_cast<uint4*>(&qbufT[((size_t)b * Nn + n0 + row) * 64 + seg * 8]) = u;
    }
#pragma unroll
    for (int m = 0; m < 2; m++) {
        int i = t + 256 * m;
        int row = i >> 3, seg = i & 7;
        uint4 u = *reinterpret_cast<const uint4*>(&Wlds[4608 + row * 72 + seg * 8]);
        *reinterpret_cast<uint4*>(&vbufT[((size_t)b * Nn + n0 + row) * 64 + seg * 8]) = u;
    }
}

// ---------------- Kernel 3: fused exp-softmax + lam contraction ----------------
#define NCHUNK 128
__global__ __launch_bounds__(256) void lamc_kernel(
    const float* __restrict__ kbuf, const ushort* __restrict__ vbufT,
    float* __restrict__ num, float* __restrict__ den) {
    int b = blockIdx.y;
    int n0 = blockIdx.x * NCHUNK;
    __shared__ float kks[Kk][NCHUNK + 1];   // holds exp(scores); 8256 B
    __shared__ ushort vvT[NCHUNK][72];      // 18432 B, rows 144 B
    __shared__ float dpart[Kk][32];         // 2048 B
    int t = threadIdx.x;
#pragma unroll
    for (int m = 0; m < 2; m++) {
        int i = t + 256 * m;
        int r = i >> 5, seg = i & 31;
        float4 f = *reinterpret_cast<const float4*>(&kbuf[((size_t)b * 16 + r) * Nn + n0 + seg * 4]);
        float e0 = __expf(f.x), e1 = __expf(f.y), e2 = __expf(f.z), e3 = __expf(f.w);
        kks[r][seg * 4 + 0] = e0;
        kks[r][seg * 4 + 1] = e1;
        kks[r][seg * 4 + 2] = e2;
        kks[r][seg * 4 + 3] = e3;
        dpart[r][seg] = e0 + e1 + e2 + e3;
    }
#pragma unroll
    for (int m = 0; m < 4; m++) {
        int i = t + 256 * m;
        int row = i >> 3, seg = i & 7;
        uint4 u = *reinterpret_cast<const uint4*>(&vbufT[((size_t)b * Nn + n0 + row) * 64 + seg * 8]);
        *reinterpret_cast<uint4*>(&vvT[row][seg * 8]) = u;
    }
    __syncthreads();
    int v = t & 63, k0 = t >> 6;
    float acc4[4] = {0.f, 0.f, 0.f, 0.f};
    for (int nl = 0; nl < NCHUNK; nl++) {
        float wv = bf2f(vvT[nl][v]);
#pragma unroll
        for (int j2 = 0; j2 < 4; j2++) acc4[j2] += kks[k0 + 4 * j2][nl] * wv;
    }
#pragma unroll
    for (int j2 = 0; j2 < 4; j2++)
        atomicAdd(&num[((size_t)b * Kk + k0 + 4 * j2) * Vv + v], acc4[j2]);
    if (t < Kk) {
        float s = 0.f;
#pragma unroll
        for (int seg = 0; seg < 32; seg++) s += dpart[t][seg];
        atomicAdd(&den[(size_t)b * Kk + t], s);
    }
}

// ---------------- Kernel 4: fused output via MFMA (in-kernel G via MFMA, no gbuf) --------
#define TN 32
__global__ __launch_bounds__(256, 4) void fused_out_kernel(
    const ushort* __restrict__ qbufT, const ushort* __restrict__ vbufT,
    const ushort* __restrict__ cwf, const float* __restrict__ num,
    const float* __restrict__ den, const float* __restrict__ conv_b,
    float* __restrict__ out) {
    __shared__ ushort Af[12 * 64 * 8];      // 12288 B
    __shared__ ushort Sf[4][12 * 32 * 8];   // 24576 B
    __shared__ ushort Qf[4][2 * 64 * 8];    // [h][(nt*64+l)*8+j]; 8192 B

    int b = blockIdx.y;
    int n0 = blockIdx.x * TN;
    int t = threadIdx.x;
    int l = t & 63;

    // ---- issue all global loads first ----
    uint4 vld0 = {0, 0, 0, 0}, vld1 = {0, 0, 0, 0};
    {
        int c = t >> 3, vg = t & 7;
        int n = n0 - 11 + c;
        if (n >= 0 && n < Nn)
            vld0 = *reinterpret_cast<const uint4*>(&vbufT[((size_t)b * Nn + n) * 64 + vg * 8]);
        int i2 = t + 256;
        if (i2 < 432) {
            int c2 = i2 >> 3, vg2 = i2 & 7;
            int n2 = n0 - 11 + c2;
            if (n2 >= 0 && n2 < Nn)
                vld1 = *reinterpret_cast<const uint4*>(&vbufT[((size_t)b * Nn + n2) * 64 + vg2 * 8]);
        }
    }
    uint2 qld0, qld1;
    {
        int i = t;          // k = i>>5, nl = i&31
        qld0 = *reinterpret_cast<const uint2*>(
            &qbufT[((size_t)b * Nn + n0 + (i & 31)) * 64 + (i >> 5) * 4]);
        int i2 = t + 256;
        qld1 = *reinterpret_cast<const uint2*>(
            &qbufT[((size_t)b * Nn + n0 + (i2 & 31)) * 64 + (i2 >> 5) * 4]);
    }
    // cw^T fragments (uniform across blocks -> L2 broadcast)
    uint4 cwld0 = *reinterpret_cast<const uint4*>(&cwf[(0 * 64 + l) * 8]);
    uint4 cwld1 = *reinterpret_cast<const uint4*>(&cwf[(1 * 64 + l) * 8]);
    float4 lcl = *reinterpret_cast<const float4*>(&num[(size_t)b * Kk * Vv + t * 4]);
    float dk = den[(size_t)b * Kk + (t >> 4)];
    float cb = conv_b[t >> 4];

    // ---- zero-init fragments ----
    uint4 z4 = {0, 0, 0, 0};
#pragma unroll
    for (int m = 0; m < 3; m++) reinterpret_cast<uint4*>(Af)[t + 256 * m] = z4;
#pragma unroll
    for (int m = 0; m < 6; m++) reinterpret_cast<uint4*>(Sf)[t + 256 * m] = z4;
#pragma unroll
    for (int m = 0; m < 2; m++) reinterpret_cast<uint4*>(Qf)[t + 256 * m] = z4;
    __syncthreads();

    // ---- scatter fills ----
    // vv -> A cols 0..53
    {
        int c = t >> 3, vg = t & 7;
        int kk = c >> 5, hi = (c >> 3) & 3, j = c & 7;
        ushort* base = &Af[((kk * 4 + hi) * 64 + vg * 8) * 8 + j];
        uint va[4] = {vld0.x, vld0.y, vld0.z, vld0.w};
#pragma unroll
        for (int e = 0; e < 4; e++) {
            base[(2 * e + 0) * 8] = (ushort)(va[e] & 0xffff);
            base[(2 * e + 1) * 8] = (ushort)(va[e] >> 16);
        }
        int i2 = t + 256;
        if (i2 < 432) {
            int c2 = i2 >> 3, vg2 = i2 & 7;
            int kk2 = c2 >> 5, hi2 = (c2 >> 3) & 3, j2 = c2 & 7;
            ushort* base2 = &Af[((kk2 * 4 + hi2) * 64 + vg2 * 8) * 8 + j2];
            uint vb4[4] = {vld1.x, vld1.y, vld1.z, vld1.w};
#pragma unroll
            for (int e = 0; e < 4; e++) {
                base2[(2 * e + 0) * 8] = (ushort)(vb4[e] & 0xffff);
                base2[(2 * e + 1) * 8] = (ushort)(vb4[e] >> 16);
            }
        }
    }
    // lc = num/den + cb -> A cols 54..69
    {
        int k = t >> 4, v0 = (t & 15) * 4;
        int c = 54 + k;
        int kk = c >> 5, hi = (c >> 3) & 3, j = c & 7;
        ushort* base = &Af[((kk * 4 + hi) * 64 + v0) * 8 + j];
        float inv = 1.f / dk;
        base[0]  = f2bf(lcl.x * inv + cb);
        base[8]  = f2bf(lcl.y * inv + cb);
        base[16] = f2bf(lcl.z * inv + cb);
        base[24] = f2bf(lcl.w * inv + cb);
    }
    // q -> S rows 54..69 AND Qf B-fragments
    {
        int i = t;
        {
            int k = i >> 5, nl = i & 31, m = 54 + k;
            int kk = m >> 5, hi = (m >> 3) & 3, j = m & 7;
            int off = ((kk * 4 + hi) * 32 + nl) * 8 + j;
            Sf[0][off] = (ushort)(qld0.x & 0xffff);
            Sf[1][off] = (ushort)(qld0.x >> 16);
            Sf[2][off] = (ushort)(qld0.y & 0xffff);
            Sf[3][off] = (ushort)(qld0.y >> 16);
            int nt = nl >> 4, lmq = nl & 15;
            int qoff = (nt * 64 + (k >> 3) * 16 + lmq) * 8 + (k & 7);
            Qf[0][qoff] = (ushort)(qld0.x & 0xffff);
            Qf[1][qoff] = (ushort)(qld0.x >> 16);
            Qf[2][qoff] = (ushort)(qld0.y & 0xffff);
            Qf[3][qoff] = (ushort)(qld0.y >> 16);
        }
        int i2 = t + 256;
        {
            int k = i2 >> 5, nl = i2 & 31, m = 54 + k;
            int kk = m >> 5, hi = (m >> 3) & 3, j = m & 7;
            int off = ((kk * 4 + hi) * 32 + nl) * 8 + j;
            Sf[0][off] = (ushort)(qld1.x & 0xffff);
            Sf[1][off] = (ushort)(qld1.x >> 16);
            Sf[2][off] = (ushort)(qld1.y & 0xffff);
            Sf[3][off] = (ushort)(qld1.y >> 16);
            int nt = nl >> 4, lmq = nl & 15;
            int qoff = (nt * 64 + (k >> 3) * 16 + lmq) * 8 + (k & 7);
            Qf[0][qoff] = (ushort)(qld1.x & 0xffff);
            Qf[1][qoff] = (ushort)(qld1.x >> 16);
            Qf[2][qoff] = (ushort)(qld1.y & 0xffff);
            Qf[3][qoff] = (ushort)(qld1.y >> 16);
        }
    }
    __syncthreads();

    // ---- G-MFMA: wave h computes G_h(23x32) = cw^T x Q_h, scatters into Sf band ----
    int h = t >> 6;
    int lm = l & 15, hif = l >> 4;
    {
        bf16x8s cwfr0 = __builtin_bit_cast(bf16x8s, cwld0);
        bf16x8s cwfr1 = __builtin_bit_cast(bf16x8s, cwld1);
        f32x4 gacc[2][2];
#pragma unroll
        for (int nt = 0; nt < 2; nt++) {
            bf16x8s qfr = *reinterpret_cast<const bf16x8s*>(&Qf[h][(nt * 64 + l) * 8]);
            gacc[0][nt] = __builtin_amdgcn_mfma_f32_16x16x32_bf16(
                cwfr0, qfr, (f32x4){0.f, 0.f, 0.f, 0.f}, 0, 0, 0);
            gacc[1][nt] = __builtin_amdgcn_mfma_f32_16x16x32_bf16(
                cwfr1, qfr, (f32x4){0.f, 0.f, 0.f, 0.f}, 0, 0, 0);
        }
        // scatter G into band: r = mt*16 + hif*4 + rr, nl2 = nt*16 + lm, m = nl2 + r
#pragma unroll
        for (int mt = 0; mt < 2; mt++)
#pragma unroll
            for (int nt = 0; nt < 2; nt++)
#pragma unroll
                for (int rr = 0; rr < 4; rr++) {
                    int r = mt * 16 + hif * 4 + rr;
                    if (r < Rr) {
                        int nl2 = nt * 16 + lm;
                        int m = nl2 + r;
                        Sf[h][((m >> 3) * 32 + nl2) * 8 + (m & 7)] = f2bf(gacc[mt][nt][rr]);
                    }
                }
    }
    __syncthreads();

    // ---- main MFMA: wave = h ----
    f32x4 acc[4][2];
#pragma unroll
    for (int mt = 0; mt < 4; mt++)
#pragma unroll
        for (int nt = 0; nt < 2; nt++) acc[mt][nt] = (f32x4){0.f, 0.f, 0.f, 0.f};

#pragma unroll
    for (int kk = 0; kk < 3; kk++) {
        bf16x8s bfr[2];
#pragma unroll
        for (int nt = 0; nt < 2; nt++)
            bfr[nt] = *reinterpret_cast<const bf16x8s*>(
                &Sf[h][((kk * 4 + hif) * 32 + nt * 16 + lm) * 8]);
#pragma unroll
        for (int mt = 0; mt < 4; mt++) {
            bf16x8s afr = *reinterpret_cast<const bf16x8s*>(
                &Af[((kk * 4 + hif) * 64 + mt * 16 + lm) * 8]);
#pragma unroll
            for (int nt = 0; nt < 2; nt++)
                acc[mt][nt] = __builtin_amdgcn_mfma_f32_16x16x32_bf16(afr, bfr[nt], acc[mt][nt], 0, 0, 0);
        }
    }

    // ---- store: C layout col=lane&15 (n), row=(lane>>4)*4+reg (v) ----
    float* ob = out + ((size_t)b * 256 + h * 64) * Nn + n0;
#pragma unroll
    for (int mt = 0; mt < 4; mt++)
#pragma unroll
        for (int nt = 0; nt < 2; nt++)
#pragma unroll
            for (int rr = 0; rr < 4; rr++) {
                int v = mt * 16 + hif * 4 + rr;
                ob[(size_t)v * Nn + nt * 16 + lm] = acc[mt][nt][rr];
            }
}

extern "C" void kernel_launch(void* const* d_in, const int* in_sizes, int n_in,
                              void* d_out, int out_size, void* d_ws, size_t ws_size,
                              hipStream_t stream) {
    const float* x      = (const float*)d_in[0];
    const float* Wq     = (const float*)d_in[1];
    const float* qg     = (const float*)d_in[2];
    const float* qb     = (const float*)d_in[3];
    const float* qm     = (const float*)d_in[4];
    const float* qv     = (const float*)d_in[5];
    const float* Wk     = (const float*)d_in[6];
    const float* Wv     = (const float*)d_in[7];
    const float* vg     = (const float*)d_in[8];
    const float* vb     = (const float*)d_in[9];
    const float* vm     = (const float*)d_in[10];
    const float* vvar   = (const float*)d_in[11];
    const float* conv_w = (const float*)d_in[12];
    const float* conv_b = (const float*)d_in[13];
    float* out = (float*)d_out;

    float* wsf = (float*)d_ws;
    ushort* Wf16  = (ushort*)wsf;                       // 36864 u16 = 18432 f
    float*  bias  = wsf + 18432;                        // 256 f
    float*  kbuf  = wsf + 18688;                        // 16*16*4096 = 1048576 f
    float*  num   = wsf + 1067264;                      // 16384 f
    float*  den   = wsf + 1083648;                      // 256 f
    ushort* cwf   = (ushort*)(wsf + 1083904);           // 1024 u16
    ushort* qbufT = (ushort*)(wsf + 1084928);           // 16*4096*64 u16 = 2097152 f
    ushort* vbufT = (ushort*)(wsf + 3182080);           // 16*4096*64 u16

    pack_kernel<<<Cc, 256, 0, stream>>>(Wq, qg, qb, qm, qv, Wk, Wv, vg, vb, vm, vvar,
                                        conv_w, Wf16, bias, cwf, num, den);
    proj_mfma_kernel<<<dim3(Nn / 64, Bn), 256, 0, stream>>>(x, Wf16, bias,
                                                            qbufT, kbuf, vbufT);
    lamc_kernel<<<dim3(Nn / NCHUNK, Bn), 256, 0, stream>>>(kbuf, vbufT, num, den);
    fused_out_kernel<<<dim3(Nn / TN, Bn), 256, 0, stream>>>(qbufT, vbufT, cwf, num, den,
                                                            conv_b, out);
}

// Round 23
// 50.011 us; speedup vs baseline: 8.9519x; 1.1077x over previous
//
#include <hip/hip_runtime.h>
#include <hip/hip_bf16.h>

typedef unsigned int uint;
typedef unsigned short ushort;

// Dims
#define Bn 16
#define Dd 256
#define Nn 4096
#define Hh 4
#define Kk 16
#define Vv 64
#define Rr 23
#define Cc 144   // 64 q + 16 k + 64 v
#define NRT 9    // 144/16 row-tiles

typedef short bf16x8s __attribute__((ext_vector_type(8)));
typedef float f32x4 __attribute__((ext_vector_type(4)));

static __device__ __forceinline__ ushort f2bf(float f) {
    __hip_bfloat16 h = __float2bfloat16(f);
    return __builtin_bit_cast(ushort, h);
}
static __device__ __forceinline__ float bf2f(ushort u) {
    return __uint_as_float(((uint)u) << 16);
}
static __device__ __forceinline__ float bflo(uint u) { return __uint_as_float(u << 16); }
static __device__ __forceinline__ float bfhi(uint u) { return __uint_as_float(u & 0xffff0000u); }

// ---------------- Kernel 1: pack weights + cw fragments + zero num/den ----------------
__global__ __launch_bounds__(256) void pack_kernel(
    const float* __restrict__ Wq, const float* __restrict__ qg, const float* __restrict__ qb,
    const float* __restrict__ qm, const float* __restrict__ qv,
    const float* __restrict__ Wk, const float* __restrict__ Wv,
    const float* __restrict__ vg, const float* __restrict__ vb,
    const float* __restrict__ vm, const float* __restrict__ vvar,
    const float* __restrict__ conv_w,
    ushort* __restrict__ Wf16, float* __restrict__ bias,
    ushort* __restrict__ cwf, float* __restrict__ num, float* __restrict__ den) {
    int c = blockIdx.x;       // 0..143
    int t = threadIdx.x;      // 0..255
    int d = t;
    float scale, bs;
    const float* src;
    if (c < 64) {
        scale = qg[c] * rsqrtf(qv[c] + 1e-5f);
        bs = qb[c] - qm[c] * scale;
        src = Wq + c * Dd;
    } else if (c < 80) {
        scale = 1.f; bs = 0.f;
        src = Wk + (c - 64) * Dd;
    } else {
        int j = c - 80;
        scale = vg[j] * rsqrtf(vvar[j] + 1e-5f);
        bs = vb[j] - vm[j] * scale;
        src = Wv + j * Dd;
    }
    int rt = c >> 4, lm = c & 15;
    int kk = d >> 5, hi = (d >> 3) & 3, j = d & 7;
    Wf16[((rt * 8 + kk) * 64 + hi * 16 + lm) * 8 + j] = f2bf(src[d] * scale);
    if (d == 0) bias[c] = bs;

    // block 0: cw^T A-fragments, tile stride 512 (64 lanes x 8 elems)
    if (c == 0) {
#pragma unroll
        for (int m = 0; m < 4; m++) {
            int flat = t + 256 * m;           // 0..1023
            int mt = flat >> 9, rem = flat & 511;
            int l = rem >> 3, jj = rem & 7;
            int r = mt * 16 + (l & 15);
            int k = (l >> 4) * 8 + jj;
            float v = (r < Rr && k < Kk) ? conv_w[k * Rr + r] : 0.f;
            cwf[flat] = f2bf(v);
        }
    }
    // block 1: zero num (16384 f) and den (256 f)
    if (c == 1) {
        float4 z = {0.f, 0.f, 0.f, 0.f};
#pragma unroll
        for (int m = 0; m < 16; m++)
            reinterpret_cast<float4*>(num)[t + 256 * m] = z;
        if (t < 64) reinterpret_cast<float4*>(den)[t] = z;
    }
}

// ---------------- Kernel 2: MFMA projection + fused exp/lam contraction ----------------
// Epilogue now also: e = exp(k-score) -> eks in LDS; num[k][v] += e*vv; den[k] += e.
// kbuf eliminated entirely.
__global__ __launch_bounds__(256, 4) void proj_mfma_kernel(
    const float* __restrict__ x, const ushort* __restrict__ Wf16,
    const float* __restrict__ bias,
    ushort* __restrict__ qbufT, ushort* __restrict__ vbufT,
    float* __restrict__ num, float* __restrict__ den) {
    __shared__ ushort Wlds[NRT * 2 * 64 * 8];   // 18432 B (2 k-steps per phase)

    int b = blockIdx.y;
    int n0 = blockIdx.x * 64;
    int t = threadIdx.x;
    int w = t >> 6, l = t & 63;
    int lm = l & 15, hi = l >> 4;
    int n = n0 + w * 16 + lm;     // this lane's output column

    const uint* WfU = (const uint*)Wf16;
    uint* WldsU = (uint*)Wlds;

    f32x4 acc[NRT];
#pragma unroll
    for (int rt = 0; rt < NRT; rt++) acc[rt] = (f32x4){0.f, 0.f, 0.f, 0.f};

    const float* xb = x + (size_t)b * Dd * Nn + n;

#pragma unroll
    for (int p = 0; p < 4; p++) {
        int kb = p * 2;
        if (p) __syncthreads();
#pragma unroll
        for (int i = 0; i < 18; i++) {
            int flat = t + 256 * i;
            int f2 = flat >> 8;          // rt*2 + kkl
            int rt = f2 >> 1, kkl = f2 & 1;
            WldsU[flat] = WfU[((rt * 8 + kb + kkl) << 8) + (flat & 255)];
        }
        __syncthreads();

#pragma unroll
        for (int kkl = 0; kkl < 2; kkl++) {
            int kk = kb + kkl;
            const float* xp = xb + (size_t)(kk * 32 + hi * 8) * Nn;
            float f[8];
#pragma unroll
            for (int j = 0; j < 8; j++) f[j] = xp[(size_t)j * Nn];
            bf16x8s bfrag;
#pragma unroll
            for (int j = 0; j < 8; j++) bfrag[j] = (short)f2bf(f[j]);
#pragma unroll
            for (int rt = 0; rt < NRT; rt++) {
                bf16x8s afrag = *reinterpret_cast<const bf16x8s*>(
                    &Wlds[(size_t)((rt * 2 + kkl) * 64 + l) * 8]);
                acc[rt] = __builtin_amdgcn_mfma_f32_16x16x32_bf16(afrag, bfrag, acc[rt], 0, 0, 0);
            }
        }
    }

    __syncthreads();   // done reading Wlds; reuse as transpose buffer
    // layout (ushort offsets): q = nl*72 + k*4 + h (rows 0..63), v = 4608 + nl*72 + v
    {
        int nl = w * 16 + lm;
#pragma unroll
        for (int rt = 0; rt < 4; rt++)
#pragma unroll
            for (int rr = 0; rr < 4; rr++) {
                int kq = hi * 4 + rr;
                Wlds[nl * 72 + kq * 4 + rt] = f2bf(acc[rt][rr] + bias[rt * 16 + kq]);
            }
#pragma unroll
        for (int rt = 5; rt < 9; rt++)
#pragma unroll
            for (int rr = 0; rr < 4; rr++) {
                int v = (rt - 5) * 16 + hi * 4 + rr;
                Wlds[4608 + nl * 72 + v] = f2bf(acc[rt][rr] + bias[80 + v]);
            }
    }
    __syncthreads();

    // ---- coalesced stores from LDS ----
#pragma unroll
    for (int m = 0; m < 2; m++) {
        int i = t + 256 * m;
        int row = i >> 3, seg = i & 7;
        uint4 u = *reinterpret_cast<const uint4*>(&Wlds[row * 72 + seg * 8]);
        *reinterpret_cast<uint4*>(&qbufT[((size_t)b * Nn + n0 + row) * 64 + seg * 8]) = u;
    }
#pragma unroll
    for (int m = 0; m < 2; m++) {
        int i = t + 256 * m;
        int row = i >> 3, seg = i & 7;
        uint4 u = *reinterpret_cast<const uint4*>(&Wlds[4608 + row * 72 + seg * 8]);
        *reinterpret_cast<uint4*>(&vbufT[((size_t)b * Nn + n0 + row) * 64 + seg * 8]) = u;
    }

    // ---- fused exp + lam contraction (replaces lamc_kernel; kbuf eliminated) ----
    float ev[4];
#pragma unroll
    for (int rr = 0; rr < 4; rr++)
        ev[rr] = __expf(acc[4][rr] + bias[64 + hi * 4 + rr]);
    __syncthreads();   // q-region LDS reads (stores above) complete before overwrite
    float* eks = reinterpret_cast<float*>(Wlds);   // eks[k][n]: 16x64 fp32 = 4096 B (q region)
    {
        int nl = w * 16 + lm;
#pragma unroll
        for (int rr = 0; rr < 4; rr++)
            eks[(hi * 4 + rr) * 64 + nl] = ev[rr];
    }
    __syncthreads();
    {
        int v = t & 63, k0 = t >> 6;
        float a4[4] = {0.f, 0.f, 0.f, 0.f};
        for (int nl = 0; nl < 64; nl++) {
            float wv = bf2f(Wlds[4608 + nl * 72 + v]);
#pragma unroll
            for (int j2 = 0; j2 < 4; j2++)
                a4[j2] += eks[(k0 + 4 * j2) * 64 + nl] * wv;
        }
#pragma unroll
        for (int j2 = 0; j2 < 4; j2++)
            atomicAdd(&num[((size_t)b * Kk + k0 + 4 * j2) * Vv + v], a4[j2]);
        if (t < Kk) {
            float s = 0.f;
#pragma unroll
            for (int nl = 0; nl < 64; nl++) s += eks[t * 64 + nl];
            atomicAdd(&den[(size_t)b * Kk + t], s);
        }
    }
}

// ---------------- Kernel 3: fused output via MFMA (R22 verified version) ----------------
#define TN 32
__global__ __launch_bounds__(256, 4) void fused_out_kernel(
    const ushort* __restrict__ qbufT, const ushort* __restrict__ vbufT,
    const ushort* __restrict__ cwf, const float* __restrict__ num,
    const float* __restrict__ den, const float* __restrict__ conv_b,
    float* __restrict__ out) {
    __shared__ ushort Af[12 * 64 * 8];      // 12288 B
    __shared__ ushort Sf[4][12 * 32 * 8];   // 24576 B
    __shared__ ushort Qf[4][2 * 64 * 8];    // [h][(nt*64+l)*8+j]; 8192 B

    int b = blockIdx.y;
    int n0 = blockIdx.x * TN;
    int t = threadIdx.x;
    int l = t & 63;

    // ---- issue all global loads first ----
    uint4 vld0 = {0, 0, 0, 0}, vld1 = {0, 0, 0, 0};
    {
        int c = t >> 3, vg = t & 7;
        int n = n0 - 11 + c;
        if (n >= 0 && n < Nn)
            vld0 = *reinterpret_cast<const uint4*>(&vbufT[((size_t)b * Nn + n) * 64 + vg * 8]);
        int i2 = t + 256;
        if (i2 < 432) {
            int c2 = i2 >> 3, vg2 = i2 & 7;
            int n2 = n0 - 11 + c2;
            if (n2 >= 0 && n2 < Nn)
                vld1 = *reinterpret_cast<const uint4*>(&vbufT[((size_t)b * Nn + n2) * 64 + vg2 * 8]);
        }
    }
    uint2 qld0, qld1;
    {
        int i = t;          // k = i>>5, nl = i&31
        qld0 = *reinterpret_cast<const uint2*>(
            &qbufT[((size_t)b * Nn + n0 + (i & 31)) * 64 + (i >> 5) * 4]);
        int i2 = t + 256;
        qld1 = *reinterpret_cast<const uint2*>(
            &qbufT[((size_t)b * Nn + n0 + (i2 & 31)) * 64 + (i2 >> 5) * 4]);
    }
    uint4 cwld0 = *reinterpret_cast<const uint4*>(&cwf[(0 * 64 + l) * 8]);
    uint4 cwld1 = *reinterpret_cast<const uint4*>(&cwf[(1 * 64 + l) * 8]);
    float4 lcl = *reinterpret_cast<const float4*>(&num[(size_t)b * Kk * Vv + t * 4]);
    float dk = den[(size_t)b * Kk + (t >> 4)];
    float cb = conv_b[t >> 4];

    // ---- zero-init fragments ----
    uint4 z4 = {0, 0, 0, 0};
#pragma unroll
    for (int m = 0; m < 3; m++) reinterpret_cast<uint4*>(Af)[t + 256 * m] = z4;
#pragma unroll
    for (int m = 0; m < 6; m++) reinterpret_cast<uint4*>(Sf)[t + 256 * m] = z4;
#pragma unroll
    for (int m = 0; m < 2; m++) reinterpret_cast<uint4*>(Qf)[t + 256 * m] = z4;
    __syncthreads();

    // ---- scatter fills ----
    // vv -> A cols 0..53
    {
        int c = t >> 3, vg = t & 7;
        int kk = c >> 5, hi = (c >> 3) & 3, j = c & 7;
        ushort* base = &Af[((kk * 4 + hi) * 64 + vg * 8) * 8 + j];
        uint va[4] = {vld0.x, vld0.y, vld0.z, vld0.w};
#pragma unroll
        for (int e = 0; e < 4; e++) {
            base[(2 * e + 0) * 8] = (ushort)(va[e] & 0xffff);
            base[(2 * e + 1) * 8] = (ushort)(va[e] >> 16);
        }
        int i2 = t + 256;
        if (i2 < 432) {
            int c2 = i2 >> 3, vg2 = i2 & 7;
            int kk2 = c2 >> 5, hi2 = (c2 >> 3) & 3, j2 = c2 & 7;
            ushort* base2 = &Af[((kk2 * 4 + hi2) * 64 + vg2 * 8) * 8 + j2];
            uint vb4[4] = {vld1.x, vld1.y, vld1.z, vld1.w};
#pragma unroll
            for (int e = 0; e < 4; e++) {
                base2[(2 * e + 0) * 8] = (ushort)(vb4[e] & 0xffff);
                base2[(2 * e + 1) * 8] = (ushort)(vb4[e] >> 16);
            }
        }
    }
    // lc = num/den + cb -> A cols 54..69
    {
        int k = t >> 4, v0 = (t & 15) * 4;
        int c = 54 + k;
        int kk = c >> 5, hi = (c >> 3) & 3, j = c & 7;
        ushort* base = &Af[((kk * 4 + hi) * 64 + v0) * 8 + j];
        float inv = 1.f / dk;
        base[0]  = f2bf(lcl.x * inv + cb);
        base[8]  = f2bf(lcl.y * inv + cb);
        base[16] = f2bf(lcl.z * inv + cb);
        base[24] = f2bf(lcl.w * inv + cb);
    }
    // q -> S rows 54..69 AND Qf B-fragments
    {
        int i = t;
        {
            int k = i >> 5, nl = i & 31, m = 54 + k;
            int kk = m >> 5, hi = (m >> 3) & 3, j = m & 7;
            int off = ((kk * 4 + hi) * 32 + nl) * 8 + j;
            Sf[0][off] = (ushort)(qld0.x & 0xffff);
            Sf[1][off] = (ushort)(qld0.x >> 16);
            Sf[2][off] = (ushort)(qld0.y & 0xffff);
            Sf[3][off] = (ushort)(qld0.y >> 16);
            int nt = nl >> 4, lmq = nl & 15;
            int qoff = (nt * 64 + (k >> 3) * 16 + lmq) * 8 + (k & 7);
            Qf[0][qoff] = (ushort)(qld0.x & 0xffff);
            Qf[1][qoff] = (ushort)(qld0.x >> 16);
            Qf[2][qoff] = (ushort)(qld0.y & 0xffff);
            Qf[3][qoff] = (ushort)(qld0.y >> 16);
        }
        int i2 = t + 256;
        {
            int k = i2 >> 5, nl = i2 & 31, m = 54 + k;
            int kk = m >> 5, hi = (m >> 3) & 3, j = m & 7;
            int off = ((kk * 4 + hi) * 32 + nl) * 8 + j;
            Sf[0][off] = (ushort)(qld1.x & 0xffff);
            Sf[1][off] = (ushort)(qld1.x >> 16);
            Sf[2][off] = (ushort)(qld1.y & 0xffff);
            Sf[3][off] = (ushort)(qld1.y >> 16);
            int nt = nl >> 4, lmq = nl & 15;
            int qoff = (nt * 64 + (k >> 3) * 16 + lmq) * 8 + (k & 7);
            Qf[0][qoff] = (ushort)(qld1.x & 0xffff);
            Qf[1][qoff] = (ushort)(qld1.x >> 16);
            Qf[2][qoff] = (ushort)(qld1.y & 0xffff);
            Qf[3][qoff] = (ushort)(qld1.y >> 16);
        }
    }
    __syncthreads();

    // ---- G-MFMA: wave h computes G_h(23x32) = cw^T x Q_h, scatters into Sf band ----
    int h = t >> 6;
    int lm = l & 15, hif = l >> 4;
    {
        bf16x8s cwfr0 = __builtin_bit_cast(bf16x8s, cwld0);
        bf16x8s cwfr1 = __builtin_bit_cast(bf16x8s, cwld1);
        f32x4 gacc[2][2];
#pragma unroll
        for (int nt = 0; nt < 2; nt++) {
            bf16x8s qfr = *reinterpret_cast<const bf16x8s*>(&Qf[h][(nt * 64 + l) * 8]);
            gacc[0][nt] = __builtin_amdgcn_mfma_f32_16x16x32_bf16(
                cwfr0, qfr, (f32x4){0.f, 0.f, 0.f, 0.f}, 0, 0, 0);
            gacc[1][nt] = __builtin_amdgcn_mfma_f32_16x16x32_bf16(
                cwfr1, qfr, (f32x4){0.f, 0.f, 0.f, 0.f}, 0, 0, 0);
        }
#pragma unroll
        for (int mt = 0; mt < 2; mt++)
#pragma unroll
            for (int nt = 0; nt < 2; nt++)
#pragma unroll
                for (int rr = 0; rr < 4; rr++) {
                    int r = mt * 16 + hif * 4 + rr;
                    if (r < Rr) {
                        int nl2 = nt * 16 + lm;
                        int m = nl2 + r;
                        Sf[h][((m >> 3) * 32 + nl2) * 8 + (m & 7)] = f2bf(gacc[mt][nt][rr]);
                    }
                }
    }
    __syncthreads();

    // ---- main MFMA: wave = h ----
    f32x4 acc[4][2];
#pragma unroll
    for (int mt = 0; mt < 4; mt++)
#pragma unroll
        for (int nt = 0; nt < 2; nt++) acc[mt][nt] = (f32x4){0.f, 0.f, 0.f, 0.f};

#pragma unroll
    for (int kk = 0; kk < 3; kk++) {
        bf16x8s bfr[2];
#pragma unroll
        for (int nt = 0; nt < 2; nt++)
            bfr[nt] = *reinterpret_cast<const bf16x8s*>(
                &Sf[h][((kk * 4 + hif) * 32 + nt * 16 + lm) * 8]);
#pragma unroll
        for (int mt = 0; mt < 4; mt++) {
            bf16x8s afr = *reinterpret_cast<const bf16x8s*>(
                &Af[((kk * 4 + hif) * 64 + mt * 16 + lm) * 8]);
#pragma unroll
            for (int nt = 0; nt < 2; nt++)
                acc[mt][nt] = __builtin_amdgcn_mfma_f32_16x16x32_bf16(afr, bfr[nt], acc[mt][nt], 0, 0, 0);
        }
    }

    // ---- store: C layout col=lane&15 (n), row=(lane>>4)*4+reg (v) ----
    float* ob = out + ((size_t)b * 256 + h * 64) * Nn + n0;
#pragma unroll
    for (int mt = 0; mt < 4; mt++)
#pragma unroll
        for (int nt = 0; nt < 2; nt++)
#pragma unroll
            for (int rr = 0; rr < 4; rr++) {
                int v = mt * 16 + hif * 4 + rr;
                ob[(size_t)v * Nn + nt * 16 + lm] = acc[mt][nt][rr];
            }
}

extern "C" void kernel_launch(void* const* d_in, const int* in_sizes, int n_in,
                              void* d_out, int out_size, void* d_ws, size_t ws_size,
                              hipStream_t stream) {
    const float* x      = (const float*)d_in[0];
    const float* Wq     = (const float*)d_in[1];
    const float* qg     = (const float*)d_in[2];
    const float* qb     = (const float*)d_in[3];
    const float* qm     = (const float*)d_in[4];
    const float* qv     = (const float*)d_in[5];
    const float* Wk     = (const float*)d_in[6];
    const float* Wv     = (const float*)d_in[7];
    const float* vg     = (const float*)d_in[8];
    const float* vb     = (const float*)d_in[9];
    const float* vm     = (const float*)d_in[10];
    const float* vvar   = (const float*)d_in[11];
    const float* conv_w = (const float*)d_in[12];
    const float* conv_b = (const float*)d_in[13];
    float* out = (float*)d_out;

    float* wsf = (float*)d_ws;
    ushort* Wf16  = (ushort*)wsf;                       // 36864 u16 = 18432 f
    float*  bias  = wsf + 18432;                        // 256 f
    float*  num   = wsf + 18688;                        // 16384 f
    float*  den   = wsf + 35072;                        // 256 f
    ushort* cwf   = (ushort*)(wsf + 35328);             // 1024 u16 = 512 f
    ushort* qbufT = (ushort*)(wsf + 35840);             // 16*4096*64 u16 = 2097152 f
    ushort* vbufT = (ushort*)(wsf + 2132992);           // 16*4096*64 u16

    pack_kernel<<<Cc, 256, 0, stream>>>(Wq, qg, qb, qm, qv, Wk, Wv, vg, vb, vm, vvar,
                                        conv_w, Wf16, bias, cwf, num, den);
    proj_mfma_kernel<<<dim3(Nn / 64, Bn), 256, 0, stream>>>(x, Wf16, bias,
                                                            qbufT, vbufT, num, den);
    fused_out_kernel<<<dim3(Nn / TN, Bn), 256, 0, stream>>>(qbufT, vbufT, cwf, num, den,
                                                            conv_b, out);
}

// Round 24
// 47.296 us; speedup vs baseline: 9.4657x; 1.0574x over previous
//
#include <hip/hip_runtime.h>
#include <hip/hip_bf16.h>

typedef unsigned int uint;
typedef unsigned short ushort;

// Dims
#define Bn 16
#define Dd 256
#define Nn 4096
#define Hh 4
#define Kk 16
#define Vv 64
#define Rr 23
#define Cc 144   // 64 q + 16 k + 64 v
#define NRT 9    // 144/16 row-tiles

typedef short bf16x8s __attribute__((ext_vector_type(8)));
typedef float f32x4 __attribute__((ext_vector_type(4)));
typedef float f32x8 __attribute__((ext_vector_type(8)));

static __device__ __forceinline__ ushort f2bf(float f) {
    __hip_bfloat16 h = __float2bfloat16(f);
    return __builtin_bit_cast(ushort, h);
}
static __device__ __forceinline__ float bf2f(ushort u) {
    return __uint_as_float(((uint)u) << 16);
}
static __device__ __forceinline__ float bflo(uint u) { return __uint_as_float(u << 16); }
static __device__ __forceinline__ float bfhi(uint u) { return __uint_as_float(u & 0xffff0000u); }

// ---------------- Kernel 1: pack weights + cw fragments + zero num/den ----------------
__global__ __launch_bounds__(256) void pack_kernel(
    const float* __restrict__ Wq, const float* __restrict__ qg, const float* __restrict__ qb,
    const float* __restrict__ qm, const float* __restrict__ qv,
    const float* __restrict__ Wk, const float* __restrict__ Wv,
    const float* __restrict__ vg, const float* __restrict__ vb,
    const float* __restrict__ vm, const float* __restrict__ vvar,
    const float* __restrict__ conv_w,
    ushort* __restrict__ Wf16, float* __restrict__ bias,
    ushort* __restrict__ cwf, float* __restrict__ num, float* __restrict__ den) {
    int c = blockIdx.x;       // 0..143
    int t = threadIdx.x;      // 0..255
    int d = t;
    float scale, bs;
    const float* src;
    if (c < 64) {
        scale = qg[c] * rsqrtf(qv[c] + 1e-5f);
        bs = qb[c] - qm[c] * scale;
        src = Wq + c * Dd;
    } else if (c < 80) {
        scale = 1.f; bs = 0.f;
        src = Wk + (c - 64) * Dd;
    } else {
        int j = c - 80;
        scale = vg[j] * rsqrtf(vvar[j] + 1e-5f);
        bs = vb[j] - vm[j] * scale;
        src = Wv + j * Dd;
    }
    int rt = c >> 4, lm = c & 15;
    int kk = d >> 5, hi = (d >> 3) & 3, j = d & 7;
    Wf16[((rt * 8 + kk) * 64 + hi * 16 + lm) * 8 + j] = f2bf(src[d] * scale);
    if (d == 0) bias[c] = bs;

    // block 0: cw^T A-fragments, tile stride 512 (64 lanes x 8 elems)
    if (c == 0) {
#pragma unroll
        for (int m = 0; m < 4; m++) {
            int flat = t + 256 * m;           // 0..1023
            int mt = flat >> 9, rem = flat & 511;
            int l = rem >> 3, jj = rem & 7;
            int r = mt * 16 + (l & 15);
            int k = (l >> 4) * 8 + jj;
            float v = (r < Rr && k < Kk) ? conv_w[k * Rr + r] : 0.f;
            cwf[flat] = f2bf(v);
        }
    }
    // block 1: zero num (16384 f) and den (256 f)
    if (c == 1) {
        float4 z = {0.f, 0.f, 0.f, 0.f};
#pragma unroll
        for (int m = 0; m < 16; m++)
            reinterpret_cast<float4*>(num)[t + 256 * m] = z;
        if (t < 64) reinterpret_cast<float4*>(den)[t] = z;
    }
}

// ---------------- Kernel 2: MFMA projection + fused exp/lam contraction ----------------
// x loads register-double-buffered across phases (f32x8 named vectors): next phase's 16
// values issue during current phase's MFMAs, drain at the next barrier -> latency hidden.
__global__ __launch_bounds__(256, 4) void proj_mfma_kernel(
    const float* __restrict__ x, const ushort* __restrict__ Wf16,
    const float* __restrict__ bias,
    ushort* __restrict__ qbufT, ushort* __restrict__ vbufT,
    float* __restrict__ num, float* __restrict__ den) {
    __shared__ ushort Wlds[NRT * 2 * 64 * 8];   // 18432 B (2 k-steps per phase)

    int b = blockIdx.y;
    int n0 = blockIdx.x * 64;
    int t = threadIdx.x;
    int w = t >> 6, l = t & 63;
    int lm = l & 15, hi = l >> 4;
    int n = n0 + w * 16 + lm;     // this lane's output column

    const uint* WfU = (const uint*)Wf16;
    uint* WldsU = (uint*)Wlds;

    f32x4 acc[NRT];
#pragma unroll
    for (int rt = 0; rt < NRT; rt++) acc[rt] = (f32x4){0.f, 0.f, 0.f, 0.f};

    const float* xb = x + (size_t)b * Dd * Nn + n;

    auto load8 = [&](int kk) -> f32x8 {
        const float* xp = xb + (size_t)(kk * 32 + hi * 8) * Nn;
        f32x8 r;
        r[0] = xp[0];
        r[1] = xp[(size_t)1 * Nn];
        r[2] = xp[(size_t)2 * Nn];
        r[3] = xp[(size_t)3 * Nn];
        r[4] = xp[(size_t)4 * Nn];
        r[5] = xp[(size_t)5 * Nn];
        r[6] = xp[(size_t)6 * Nn];
        r[7] = xp[(size_t)7 * Nn];
        return r;
    };
    auto cvt8 = [&](f32x8 f) -> bf16x8s {
        bf16x8s o;
#pragma unroll
        for (int j = 0; j < 8; j++) o[j] = (short)f2bf(f[j]);
        return o;
    };

    f32x8 xc0 = load8(0), xc1 = load8(1);
    f32x8 xn0 = xc0, xn1 = xc1;

#pragma unroll
    for (int p = 0; p < 4; p++) {
        int kb = p * 2;
        if (p) __syncthreads();
#pragma unroll
        for (int i = 0; i < 18; i++) {
            int flat = t + 256 * i;
            int f2 = flat >> 8;          // rt*2 + kkl
            int rt = f2 >> 1, kkl = f2 & 1;
            WldsU[flat] = WfU[((rt * 8 + kb + kkl) << 8) + (flat & 255)];
        }
        __syncthreads();

        bf16x8s bf0 = cvt8(xc0);
        bf16x8s bf1 = cvt8(xc1);
        if (p < 3) {                     // prefetch next phase during MFMAs
            xn0 = load8(kb + 2);
            xn1 = load8(kb + 3);
        }
#pragma unroll
        for (int rt = 0; rt < NRT; rt++) {
            bf16x8s afrag = *reinterpret_cast<const bf16x8s*>(
                &Wlds[(size_t)((rt * 2 + 0) * 64 + l) * 8]);
            acc[rt] = __builtin_amdgcn_mfma_f32_16x16x32_bf16(afrag, bf0, acc[rt], 0, 0, 0);
        }
#pragma unroll
        for (int rt = 0; rt < NRT; rt++) {
            bf16x8s afrag = *reinterpret_cast<const bf16x8s*>(
                &Wlds[(size_t)((rt * 2 + 1) * 64 + l) * 8]);
            acc[rt] = __builtin_amdgcn_mfma_f32_16x16x32_bf16(afrag, bf1, acc[rt], 0, 0, 0);
        }
        xc0 = xn0;
        xc1 = xn1;
    }

    __syncthreads();   // done reading Wlds; reuse as transpose buffer
    // layout (ushort offsets): q = nl*72 + k*4 + h (rows 0..63), v = 4608 + nl*72 + v
    {
        int nl = w * 16 + lm;
#pragma unroll
        for (int rt = 0; rt < 4; rt++)
#pragma unroll
            for (int rr = 0; rr < 4; rr++) {
                int kq = hi * 4 + rr;
                Wlds[nl * 72 + kq * 4 + rt] = f2bf(acc[rt][rr] + bias[rt * 16 + kq]);
            }
#pragma unroll
        for (int rt = 5; rt < 9; rt++)
#pragma unroll
            for (int rr = 0; rr < 4; rr++) {
                int v = (rt - 5) * 16 + hi * 4 + rr;
                Wlds[4608 + nl * 72 + v] = f2bf(acc[rt][rr] + bias[80 + v]);
            }
    }
    __syncthreads();

    // ---- coalesced stores from LDS ----
#pragma unroll
    for (int m = 0; m < 2; m++) {
        int i = t + 256 * m;
        int row = i >> 3, seg = i & 7;
        uint4 u = *reinterpret_cast<const uint4*>(&Wlds[row * 72 + seg * 8]);
        *reinterpret_cast<uint4*>(&qbufT[((size_t)b * Nn + n0 + row) * 64 + seg * 8]) = u;
    }
#pragma unroll
    for (int m = 0; m < 2; m++) {
        int i = t + 256 * m;
        int row = i >> 3, seg = i & 7;
        uint4 u = *reinterpret_cast<const uint4*>(&Wlds[4608 + row * 72 + seg * 8]);
        *reinterpret_cast<uint4*>(&vbufT[((size_t)b * Nn + n0 + row) * 64 + seg * 8]) = u;
    }

    // ---- fused exp + lam contraction (kbuf eliminated) ----
    float ev[4];
#pragma unroll
    for (int rr = 0; rr < 4; rr++)
        ev[rr] = __expf(acc[4][rr] + bias[64 + hi * 4 + rr]);
    __syncthreads();   // q-region LDS reads (stores above) complete before overwrite
    float* eks = reinterpret_cast<float*>(Wlds);   // eks[k][n]: 16x64 fp32 (q region)
    {
        int nl = w * 16 + lm;
#pragma unroll
        for (int rr = 0; rr < 4; rr++)
            eks[(hi * 4 + rr) * 64 + nl] = ev[rr];
    }
    __syncthreads();
    {
        int v = t & 63, k0 = t >> 6;
        float a4[4] = {0.f, 0.f, 0.f, 0.f};
        for (int nl = 0; nl < 64; nl++) {
            float wv = bf2f(Wlds[4608 + nl * 72 + v]);
#pragma unroll
            for (int j2 = 0; j2 < 4; j2++)
                a4[j2] += eks[(k0 + 4 * j2) * 64 + nl] * wv;
        }
#pragma unroll
        for (int j2 = 0; j2 < 4; j2++)
            atomicAdd(&num[((size_t)b * Kk + k0 + 4 * j2) * Vv + v], a4[j2]);
        if (t < Kk) {
            float s = 0.f;
#pragma unroll
            for (int nl = 0; nl < 64; nl++) s += eks[t * 64 + nl];
            atomicAdd(&den[(size_t)b * Kk + t], s);
        }
    }
}

// ---------------- Kernel 3: fused output via MFMA (R22 verified version) ----------------
#define TN 32
__global__ __launch_bounds__(256, 4) void fused_out_kernel(
    const ushort* __restrict__ qbufT, const ushort* __restrict__ vbufT,
    const ushort* __restrict__ cwf, const float* __restrict__ num,
    const float* __restrict__ den, const float* __restrict__ conv_b,
    float* __restrict__ out) {
    __shared__ ushort Af[12 * 64 * 8];      // 12288 B
    __shared__ ushort Sf[4][12 * 32 * 8];   // 24576 B
    __shared__ ushort Qf[4][2 * 64 * 8];    // [h][(nt*64+l)*8+j]; 8192 B

    int b = blockIdx.y;
    int n0 = blockIdx.x * TN;
    int t = threadIdx.x;
    int l = t & 63;

    // ---- issue all global loads first ----
    uint4 vld0 = {0, 0, 0, 0}, vld1 = {0, 0, 0, 0};
    {
        int c = t >> 3, vg = t & 7;
        int n = n0 - 11 + c;
        if (n >= 0 && n < Nn)
            vld0 = *reinterpret_cast<const uint4*>(&vbufT[((size_t)b * Nn + n) * 64 + vg * 8]);
        int i2 = t + 256;
        if (i2 < 432) {
            int c2 = i2 >> 3, vg2 = i2 & 7;
            int n2 = n0 - 11 + c2;
            if (n2 >= 0 && n2 < Nn)
                vld1 = *reinterpret_cast<const uint4*>(&vbufT[((size_t)b * Nn + n2) * 64 + vg2 * 8]);
        }
    }
    uint2 qld0, qld1;
    {
        int i = t;          // k = i>>5, nl = i&31
        qld0 = *reinterpret_cast<const uint2*>(
            &qbufT[((size_t)b * Nn + n0 + (i & 31)) * 64 + (i >> 5) * 4]);
        int i2 = t + 256;
        qld1 = *reinterpret_cast<const uint2*>(
            &qbufT[((size_t)b * Nn + n0 + (i2 & 31)) * 64 + (i2 >> 5) * 4]);
    }
    uint4 cwld0 = *reinterpret_cast<const uint4*>(&cwf[(0 * 64 + l) * 8]);
    uint4 cwld1 = *reinterpret_cast<const uint4*>(&cwf[(1 * 64 + l) * 8]);
    float4 lcl = *reinterpret_cast<const float4*>(&num[(size_t)b * Kk * Vv + t * 4]);
    float dk = den[(size_t)b * Kk + (t >> 4)];
    float cb = conv_b[t >> 4];

    // ---- zero-init fragments (Af slices 0..7 fully overwritten; zero only 8..11) ----
    uint4 z4 = {0, 0, 0, 0};
    reinterpret_cast<uint4*>(Af)[512 + t] = z4;
#pragma unroll
    for (int m = 0; m < 6; m++) reinterpret_cast<uint4*>(Sf)[t + 256 * m] = z4;
#pragma unroll
    for (int m = 0; m < 2; m++) reinterpret_cast<uint4*>(Qf)[t + 256 * m] = z4;
    __syncthreads();

    // ---- scatter fills ----
    // vv -> A cols 0..53
    {
        int c = t >> 3, vg = t & 7;
        int kk = c >> 5, hi = (c >> 3) & 3, j = c & 7;
        ushort* base = &Af[((kk * 4 + hi) * 64 + vg * 8) * 8 + j];
        uint va[4] = {vld0.x, vld0.y, vld0.z, vld0.w};
#pragma unroll
        for (int e = 0; e < 4; e++) {
            base[(2 * e + 0) * 8] = (ushort)(va[e] & 0xffff);
            base[(2 * e + 1) * 8] = (ushort)(va[e] >> 16);
        }
        int i2 = t + 256;
        if (i2 < 432) {
            int c2 = i2 >> 3, vg2 = i2 & 7;
            int kk2 = c2 >> 5, hi2 = (c2 >> 3) & 3, j2 = c2 & 7;
            ushort* base2 = &Af[((kk2 * 4 + hi2) * 64 + vg2 * 8) * 8 + j2];
            uint vb4[4] = {vld1.x, vld1.y, vld1.z, vld1.w};
#pragma unroll
            for (int e = 0; e < 4; e++) {
                base2[(2 * e + 0) * 8] = (ushort)(vb4[e] & 0xffff);
                base2[(2 * e + 1) * 8] = (ushort)(vb4[e] >> 16);
            }
        }
    }
    // lc = num/den + cb -> A cols 54..69
    {
        int k = t >> 4, v0 = (t & 15) * 4;
        int c = 54 + k;
        int kk = c >> 5, hi = (c >> 3) & 3, j = c & 7;
        ushort* base = &Af[((kk * 4 + hi) * 64 + v0) * 8 + j];
        float inv = 1.f / dk;
        base[0]  = f2bf(lcl.x * inv + cb);
        base[8]  = f2bf(lcl.y * inv + cb);
        base[16] = f2bf(lcl.z * inv + cb);
        base[24] = f2bf(lcl.w * inv + cb);
    }
    // q -> S rows 54..69 AND Qf B-fragments
    {
        int i = t;
        {
            int k = i >> 5, nl = i & 31, m = 54 + k;
            int kk = m >> 5, hi = (m >> 3) & 3, j = m & 7;
            int off = ((kk * 4 + hi) * 32 + nl) * 8 + j;
            Sf[0][off] = (ushort)(qld0.x & 0xffff);
            Sf[1][off] = (ushort)(qld0.x >> 16);
            Sf[2][off] = (ushort)(qld0.y & 0xffff);
            Sf[3][off] = (ushort)(qld0.y >> 16);
            int nt = nl >> 4, lmq = nl & 15;
            int qoff = (nt * 64 + (k >> 3) * 16 + lmq) * 8 + (k & 7);
            Qf[0][qoff] = (ushort)(qld0.x & 0xffff);
            Qf[1][qoff] = (ushort)(qld0.x >> 16);
            Qf[2][qoff] = (ushort)(qld0.y & 0xffff);
            Qf[3][qoff] = (ushort)(qld0.y >> 16);
        }
        int i2 = t + 256;
        {
            int k = i2 >> 5, nl = i2 & 31, m = 54 + k;
            int kk = m >> 5, hi = (m >> 3) & 3, j = m & 7;
            int off = ((kk * 4 + hi) * 32 + nl) * 8 + j;
            Sf[0][off] = (ushort)(qld1.x & 0xffff);
            Sf[1][off] = (ushort)(qld1.x >> 16);
            Sf[2][off] = (ushort)(qld1.y & 0xffff);
            Sf[3][off] = (ushort)(qld1.y >> 16);
            int nt = nl >> 4, lmq = nl & 15;
            int qoff = (nt * 64 + (k >> 3) * 16 + lmq) * 8 + (k & 7);
            Qf[0][qoff] = (ushort)(qld1.x & 0xffff);
            Qf[1][qoff] = (ushort)(qld1.x >> 16);
            Qf[2][qoff] = (ushort)(qld1.y & 0xffff);
            Qf[3][qoff] = (ushort)(qld1.y >> 16);
        }
    }
    __syncthreads();

    // ---- G-MFMA: wave h computes G_h(23x32) = cw^T x Q_h, scatters into Sf band ----
    int h = t >> 6;
    int lm = l & 15, hif = l >> 4;
    {
        bf16x8s cwfr0 = __builtin_bit_cast(bf16x8s, cwld0);
        bf16x8s cwfr1 = __builtin_bit_cast(bf16x8s, cwld1);
        f32x4 gacc[2][2];
#pragma unroll
        for (int nt = 0; nt < 2; nt++) {
            bf16x8s qfr = *reinterpret_cast<const bf16x8s*>(&Qf[h][(nt * 64 + l) * 8]);
            gacc[0][nt] = __builtin_amdgcn_mfma_f32_16x16x32_bf16(
                cwfr0, qfr, (f32x4){0.f, 0.f, 0.f, 0.f}, 0, 0, 0);
            gacc[1][nt] = __builtin_amdgcn_mfma_f32_16x16x32_bf16(
                cwfr1, qfr, (f32x4){0.f, 0.f, 0.f, 0.f}, 0, 0, 0);
        }
#pragma unroll
        for (int mt = 0; mt < 2; mt++)
#pragma unroll
            for (int nt = 0; nt < 2; nt++)
#pragma unroll
                for (int rr = 0; rr < 4; rr++) {
                    int r = mt * 16 + hif * 4 + rr;
                    if (r < Rr) {
                        int nl2 = nt * 16 + lm;
                        int m = nl2 + r;
                        Sf[h][((m >> 3) * 32 + nl2) * 8 + (m & 7)] = f2bf(gacc[mt][nt][rr]);
                    }
                }
    }
    __syncthreads();

    // ---- main MFMA: wave = h ----
    f32x4 acc[4][2];
#pragma unroll
    for (int mt = 0; mt < 4; mt++)
#pragma unroll
        for (int nt = 0; nt < 2; nt++) acc[mt][nt] = (f32x4){0.f, 0.f, 0.f, 0.f};

#pragma unroll
    for (int kk = 0; kk < 3; kk++) {
        bf16x8s bfr[2];
#pragma unroll
        for (int nt = 0; nt < 2; nt++)
            bfr[nt] = *reinterpret_cast<const bf16x8s*>(
                &Sf[h][((kk * 4 + hif) * 32 + nt * 16 + lm) * 8]);
#pragma unroll
        for (int mt = 0; mt < 4; mt++) {
            bf16x8s afr = *reinterpret_cast<const bf16x8s*>(
                &Af[((kk * 4 + hif) * 64 + mt * 16 + lm) * 8]);
#pragma unroll
            for (int nt = 0; nt < 2; nt++)
                acc[mt][nt] = __builtin_amdgcn_mfma_f32_16x16x32_bf16(afr, bfr[nt], acc[mt][nt], 0, 0, 0);
        }
    }

    // ---- store: C layout col=lane&15 (n), row=(lane>>4)*4+reg (v) ----
    float* ob = out + ((size_t)b * 256 + h * 64) * Nn + n0;
#pragma unroll
    for (int mt = 0; mt < 4; mt++)
#pragma unroll
        for (int nt = 0; nt < 2; nt++)
#pragma unroll
            for (int rr = 0; rr < 4; rr++) {
                int v = mt * 16 + hif * 4 + rr;
                ob[(size_t)v * Nn + nt * 16 + lm] = acc[mt][nt][rr];
            }
}

extern "C" void kernel_launch(void* const* d_in, const int* in_sizes, int n_in,
                              void* d_out, int out_size, void* d_ws, size_t ws_size,
                              hipStream_t stream) {
    const float* x      = (const float*)d_in[0];
    const float* Wq     = (const float*)d_in[1];
    const float* qg     = (const float*)d_in[2];
    const float* qb     = (const float*)d_in[3];
    const float* qm     = (const float*)d_in[4];
    const float* qv     = (const float*)d_in[5];
    const float* Wk     = (const float*)d_in[6];
    const float* Wv     = (const float*)d_in[7];
    const float* vg     = (const float*)d_in[8];
    const float* vb     = (const float*)d_in[9];
    const float* vm     = (const float*)d_in[10];
    const float* vvar   = (const float*)d_in[11];
    const float* conv_w = (const float*)d_in[12];
    const float* conv_b = (const float*)d_in[13];
    float* out = (float*)d_out;

    float* wsf = (float*)d_ws;
    ushort* Wf16  = (ushort*)wsf;                       // 36864 u16 = 18432 f
    float*  bias  = wsf + 18432;                        // 256 f
    float*  num   = wsf + 18688;                        // 16384 f
    float*  den   = wsf + 35072;                        // 256 f
    ushort* cwf   = (ushort*)(wsf + 35328);             // 1024 u16 = 512 f
    ushort* qbufT = (ushort*)(wsf + 35840);             // 16*4096*64 u16 = 2097152 f
    ushort* vbufT = (ushort*)(wsf + 2132992);           // 16*4096*64 u16

    pack_kernel<<<Cc, 256, 0, stream>>>(Wq, qg, qb, qm, qv, Wk, Wv, vg, vb, vm, vvar,
                                        conv_w, Wf16, bias, cwf, num, den);
    proj_mfma_kernel<<<dim3(Nn / 64, Bn), 256, 0, stream>>>(x, Wf16, bias,
                                                            qbufT, vbufT, num, den);
    fused_out_kernel<<<dim3(Nn / TN, Bn), 256, 0, stream>>>(qbufT, vbufT, cwf, num, den,
                                                            conv_b, out);
}